// Round 18
// baseline (279.122 us; speedup 1.0000x reference)
//
#include <hip/hip_runtime.h>
#include <cstdint>

#define R_TOT 16384
#define T_NT  2048
#define DD    128
#define HH    512
#define MC_   20
#define BR    16             // rows per block in k3b / fallback k3
#define NBLK  1024           // R_TOT / BR
#define SPW   16             // 32-col steps per wave (64 total / 4 waves)

// Output layout (floats)
#define MASK_OFF 0
#define LOGP_OFF 16384
#define WORD_OFF 32768
#define CHAR_OFF 49152
#define EMB_OFF  376832          // 49152 + 16384*20
#define LOSS_OFF 2473984         // 376832 + 16384*128

// ws layout (float slots)
#define HDN_OFF   0              // hdn f32 [16384][512]            (8,388,608)
#define HDNB_OFF  8388608        // hdnB ushort[16384*512]          (4,194,304 slots)
#define W2T_OFF   12582912       // W2Tf f32 [2048][512]            (1,048,576)
#define W2Q_OFF   13631488       // W2q ushort[128cc][16ks][512]    (524,288 slots)
#define WTT5_OFF  14155776       // wtgtT5 ushort[64][8][512]       (131,072 slots)
#define WT_OFF    14286848       // wtgt f32 temp [2048][128]       (262,144)
#define ENT_OFF   14548992       // 1024
#define CNT_OFF   14550016       // 1024
#define S_OFF     14551040       // S bf16 ushort[16384*2048]       (16,777,216 slots)
#define WS_NEED_FLOATS (S_OFF + 16777216)

typedef __attribute__((ext_vector_type(8))) short short8v;
typedef __attribute__((ext_vector_type(4))) float f32x4;
typedef unsigned short ushort_t;

__device__ __forceinline__ ushort_t f2bf(float f) {
    union { float f; unsigned int u; } v; v.f = f;
    unsigned int r = v.u + 0x7FFFu + ((v.u >> 16) & 1u);
    return (ushort_t)(r >> 16);
}
__device__ __forceinline__ float bf2f(ushort_t u) {
    union { unsigned int u; float f; } v; v.u = ((unsigned int)u) << 16;
    return v.f;
}

// ---------------- K1: gather wtgt embeddings ----------------
__global__ __launch_bounds__(256) void k1_gather(
    const int* __restrict__ tgt_ids, const float* __restrict__ W, float* __restrict__ wtgt)
{
    int rr = blockIdx.x * 2 + (threadIdx.x >> 7);
    int d = threadIdx.x & 127;
    int wsrc = tgt_ids[rr];
    wtgt[(size_t)rr * DD + d] = W[(size_t)wsrc * DD + d];
}

// ---------------- K1b: wtgt -> wtgtT5 full-K PV B-fragment pack ----------------
__global__ __launch_bounds__(256) void k1b_wtgtT5(
    const float* __restrict__ wtgt, ushort_t* __restrict__ wtgtT5)
{
    const int sc = blockIdx.x, t = threadIdx.x;
    #pragma unroll
    for (int it = 0; it < 2; ++it) {
        int idx = it * 256 + t;
        int df = idx >> 6, lane = idx & 63;
        int lrow = lane & 15, kg = lane >> 4;
        ushort_t* dst = wtgtT5 + ((size_t)sc * 8 + df) * 512 + lane * 8;
        #pragma unroll
        for (int j = 0; j < 8; ++j) {
            int col = sc * 32 + (j < 4 ? kg * 4 + j : 16 + kg * 4 + (j - 4));
            dst[j] = f2bf(wtgt[(size_t)col * DD + df * 16 + lrow]);
        }
    }
}

// ---------------- K0: W2 -> W2Tf f32 + W2q lane-linear fragment pack ----------------
// W2q[(cc*16+ks)*512 + lane*8 + i] = bf16(W2[ks*32 + (lane>>4)*8 + i][cc*16 + (lane&15)])
__global__ __launch_bounds__(256) void k0_w2t(
    const float* __restrict__ W2, float* __restrict__ W2Tf, ushort_t* __restrict__ W2q)
{
    __shared__ float tile[32][33];
    const int js = blockIdx.x, ks = blockIdx.y;
    const int cb = js * 32, kb = ks * 32;
    const int lx = threadIdx.x & 31, ly = threadIdx.x >> 5;
    #pragma unroll
    for (int i = 0; i < 32; i += 8)
        tile[ly + i][lx] = W2[(size_t)(kb + ly + i) * T_NT + cb + lx];
    __syncthreads();
    #pragma unroll
    for (int i = 0; i < 32; i += 8) {
        int c = cb + ly + i, k = kb + lx;
        W2Tf[(size_t)c * HH + k] = tile[lx][ly + i];
    }
    if (threadIdx.x < 128) {
        int c = threadIdx.x >> 2, kgrp = threadIdx.x & 3;
        int cs = c >> 4, lrow = c & 15;
        ushort_t* dst = W2q + (size_t)(((js * 2 + cs) * 16 + ks) * 512) + (kgrp * 16 + lrow) * 8;
        #pragma unroll
        for (int i = 0; i < 8; ++i)
            dst[i] = f2bf(tile[kgrp * 8 + i][c]);
    }
}

// ---------------- K2: hdn = relu(W[inp_word] @ W1 + b1), fp32 + bf16 ----------------
__global__ __launch_bounds__(256) void k2_hdn(
    const int* __restrict__ inp_word, const float* __restrict__ W,
    const float* __restrict__ W1, const float* __restrict__ b1,
    float* __restrict__ hdn, ushort_t* __restrict__ hdnB)
{
    __shared__ float As[16][64];
    __shared__ float Bs[16][64];
    const int t = threadIdx.x;
    const int bm = blockIdx.x * 64;
    const int bn = blockIdx.y * 64;
    const int tx = t & 15, ty = t >> 4;
    float acc[4][4] = {};
    for (int k0 = 0; k0 < DD; k0 += 16) {
        {
            int m = t >> 2, kq = t & 3;
            int wsrc = inp_word[bm + m];
            float4 v = *(const float4*)(W + (size_t)wsrc * DD + k0 + kq * 4);
            As[kq * 4 + 0][m] = v.x; As[kq * 4 + 1][m] = v.y;
            As[kq * 4 + 2][m] = v.z; As[kq * 4 + 3][m] = v.w;
        }
        {
            int k = t >> 4, nq = t & 15;
            *(float4*)(&Bs[k][nq * 4]) =
                *(const float4*)(W1 + (size_t)(k0 + k) * HH + bn + nq * 4);
        }
        __syncthreads();
        #pragma unroll
        for (int k = 0; k < 16; ++k) {
            float a[4], b[4];
            #pragma unroll
            for (int i = 0; i < 4; i++) a[i] = As[k][ty * 4 + i];
            #pragma unroll
            for (int j = 0; j < 4; j++) b[j] = Bs[k][tx * 4 + j];
            #pragma unroll
            for (int i = 0; i < 4; i++)
                #pragma unroll
                for (int j = 0; j < 4; j++)
                    acc[i][j] = fmaf(a[i], b[j], acc[i][j]);
        }
        __syncthreads();
    }
    #pragma unroll
    for (int i = 0; i < 4; i++) {
        int m = bm + ty * 4 + i;
        int n = bn + tx * 4;
        float4 v;
        v.x = fmaxf(acc[i][0] + b1[n + 0], 0.f);
        v.y = fmaxf(acc[i][1] + b1[n + 1], 0.f);
        v.z = fmaxf(acc[i][2] + b1[n + 2], 0.f);
        v.w = fmaxf(acc[i][3] + b1[n + 3], 0.f);
        *(float4*)(hdn + (size_t)m * HH + n) = v;
        ushort4 hb;
        hb.x = f2bf(v.x); hb.y = f2bf(v.y); hb.z = f2bf(v.z); hb.w = f2bf(v.w);
        *(ushort4*)(hdnB + (size_t)m * HH + n) = hb;
    }
}

// ---------------- K3a: pure GEMM S = hdn @ W2 (bf16 out), fragment-direct ----------------
// grid (16 nb, 256 mb) x 256 thr. Wave wid: cc pair nb*8+wid*2. No LDS, no barriers.
__global__ __launch_bounds__(256) void k3a_gemm(
    const ushort_t* __restrict__ hdnB, const ushort_t* __restrict__ W2q,
    ushort_t* __restrict__ S)
{
    const int t = threadIdx.x;
    const int wid = t >> 6, lane = t & 63;
    const int lrow = lane & 15, kgrp = lane >> 4;
    const int nb = blockIdx.x, mb = blockIdx.y;
    const int cc0 = nb * 8 + wid * 2;

    const ushort_t* aBase = hdnB + (size_t)(mb * 64 + lrow) * HH + kgrp * 8;   // +r*16*512 +ks*32
    const ushort_t* bBase = W2q + (size_t)cc0 * 16 * 512 + lane * 8;           // +c*16*512 +ks*512

    f32x4 acc[4][2];
    #pragma unroll
    for (int r = 0; r < 4; ++r)
        #pragma unroll
        for (int c = 0; c < 2; ++c) acc[r][c] = (f32x4){0.f, 0.f, 0.f, 0.f};

    #pragma unroll
    for (int ks = 0; ks < 16; ++ks) {
        short8v af0 = *(const short8v*)(aBase + 0 * 8192 + ks * 32);
        short8v af1 = *(const short8v*)(aBase + 1 * 8192 + ks * 32);
        short8v af2 = *(const short8v*)(aBase + 2 * 8192 + ks * 32);
        short8v af3 = *(const short8v*)(aBase + 3 * 8192 + ks * 32);
        short8v bf0 = *(const short8v*)(bBase + 0 * 8192 + ks * 512);
        short8v bf1 = *(const short8v*)(bBase + 1 * 8192 + ks * 512);
        acc[0][0] = __builtin_amdgcn_mfma_f32_16x16x32_bf16(bf0, af0, acc[0][0], 0, 0, 0);
        acc[1][0] = __builtin_amdgcn_mfma_f32_16x16x32_bf16(bf0, af1, acc[1][0], 0, 0, 0);
        acc[2][0] = __builtin_amdgcn_mfma_f32_16x16x32_bf16(bf0, af2, acc[2][0], 0, 0, 0);
        acc[3][0] = __builtin_amdgcn_mfma_f32_16x16x32_bf16(bf0, af3, acc[3][0], 0, 0, 0);
        acc[0][1] = __builtin_amdgcn_mfma_f32_16x16x32_bf16(bf1, af0, acc[0][1], 0, 0, 0);
        acc[1][1] = __builtin_amdgcn_mfma_f32_16x16x32_bf16(bf1, af1, acc[1][1], 0, 0, 0);
        acc[2][1] = __builtin_amdgcn_mfma_f32_16x16x32_bf16(bf1, af2, acc[2][1], 0, 0, 0);
        acc[3][1] = __builtin_amdgcn_mfma_f32_16x16x32_bf16(bf1, af3, acc[3][1], 0, 0, 0);
    }

    // store: lane holds S[mb*64 + r*16 + lrow][(cc0+c)*16 + kgrp*4 + q]
    #pragma unroll
    for (int r = 0; r < 4; ++r) {
        #pragma unroll
        for (int c = 0; c < 2; ++c) {
            int row = mb * 64 + r * 16 + lrow;
            int col = (cc0 + c) * 16 + kgrp * 4;
            ushort4 o;
            o.x = f2bf(acc[r][c][0]); o.y = f2bf(acc[r][c][1]);
            o.z = f2bf(acc[r][c][2]); o.w = f2bf(acc[r][c][3]);
            *(ushort4*)(S + (size_t)row * T_NT + col) = o;
        }
    }
}

// ---------------- K3b: streaming stats+PV over precomputed S ----------------
// 1024 blocks x 16 rows, 4 independent col-stream waves, no in-loop barriers.
__global__ __launch_bounds__(256) void k3b_stream(
    const ushort_t* __restrict__ S, const float* __restrict__ hdn,
    const float* __restrict__ W2Tf, const float* __restrict__ b2,
    const float* __restrict__ gumbel, const int* __restrict__ inp_word,
    const int* __restrict__ keyword_table, const int* __restrict__ tgt_ids,
    const int* __restrict__ lut, const float* __restrict__ W,
    const ushort_t* __restrict__ wtgtT5,
    float* __restrict__ out, float* __restrict__ entP, float* __restrict__ cntP)
{
    __shared__ float scrS[3 * 2048];
    __shared__ float statP[4][16][8];
    __shared__ int   candS[BR * 2];
    __shared__ float invs2S[BR], entS[BR];
    __shared__ int   mskS[BR], winS[BR];

    const int t = threadIdx.x;
    const int wid = t >> 6, lane = t & 63;
    const int lrow = lane & 15, kgrp = lane >> 4;
    const int row0 = blockIdx.x * BR;
    const int scq = (int)((blockIdx.x + wid) & 3);

    const ushort_t* sRow = S + (size_t)(row0 + lrow) * T_NT + kgrp * 4;
    const float* gRow = gumbel + (size_t)(row0 + lrow) * T_NT + kgrp * 4;

    float m_ = -1e30f, sE_ = 0.f, sEl_ = 0.f, s2_ = 0.f;
    float a1_ = -1e30f, a2_ = -1e30f;
    int i1_ = 0, i2_ = 0;
    f32x4 accpv[8];
    #pragma unroll
    for (int df = 0; df < 8; ++df) accpv[df] = (f32x4){0.f, 0.f, 0.f, 0.f};

    // step-0 prefetch
    ushort4 sa = *(const ushort4*)(sRow + scq * 32);
    ushort4 sb = *(const ushort4*)(sRow + scq * 32 + 16);
    f32x4 ga = *(const f32x4*)(gRow + scq * 32);
    f32x4 gb = *(const f32x4*)(gRow + scq * 32 + 16);

    for (int s = 0; s < SPW; ++s) {
        const int sc = scq + 4 * s;
        const int scn = scq + 4 * ((s + 1) & 15);

        ushort4 san = *(const ushort4*)(sRow + scn * 32);
        ushort4 sbn = *(const ushort4*)(sRow + scn * 32 + 16);
        f32x4 gna = *(const f32x4*)(gRow + scn * 32);
        f32x4 gnb = *(const f32x4*)(gRow + scn * 32 + 16);

        f32x4 b2a = *(const f32x4*)(b2 + sc * 32 + kgrp * 4);
        f32x4 b2b = *(const f32x4*)(b2 + sc * 32 + kgrp * 4 + 16);

        const ushort_t* vt = wtgtT5 + (size_t)sc * 4096 + lane * 8;
        short8v bvf[8];
        #pragma unroll
        for (int df = 0; df < 8; ++df) bvf[df] = *(const short8v*)(vt + df * 512);

        ushort_t sa_[4] = {sa.x, sa.y, sa.z, sa.w};
        ushort_t sb_[4] = {sb.x, sb.y, sb.z, sb.w};

        short8v pav;
        const int colb = sc * 32 + kgrp * 4;
        #pragma unroll
        for (int q = 0; q < 4; ++q) {
            float l0 = bf2f(sa_[q]) + b2a[q];
            m_ = fmaxf(m_, l0);
            float e0 = __expf(l0);
            sE_ += e0; sEl_ = fmaf(e0, l0, sEl_);
            float aa0 = l0 + ga[q];
            float p0 = __expf(2.0f * aa0);
            s2_ += p0;
            if (aa0 > a1_) { a2_ = a1_; i2_ = i1_; a1_ = aa0; i1_ = colb + q; }
            else if (aa0 > a2_) { a2_ = aa0; i2_ = colb + q; }
            pav[q] = (short)f2bf(p0);

            float l1 = bf2f(sb_[q]) + b2b[q];
            m_ = fmaxf(m_, l1);
            float e1 = __expf(l1);
            sE_ += e1; sEl_ = fmaf(e1, l1, sEl_);
            float aa1 = l1 + gb[q];
            float p1 = __expf(2.0f * aa1);
            s2_ += p1;
            if (aa1 > a1_) { a2_ = a1_; i2_ = i1_; a1_ = aa1; i1_ = colb + 16 + q; }
            else if (aa1 > a2_) { a2_ = aa1; i2_ = colb + 16 + q; }
            pav[4 + q] = (short)f2bf(p1);
        }

        #pragma unroll
        for (int df = 0; df < 8; ++df)
            accpv[df] = __builtin_amdgcn_mfma_f32_16x16x32_bf16(pav, bvf[df], accpv[df], 0, 0, 0);

        sa = san; sb = sbn; ga = gna; gb = gnb;
    }

    // in-wave reduction across kgrp
    #pragma unroll
    for (int mk = 16; mk < 64; mk <<= 1) {
        m_ = fmaxf(m_, __shfl_xor(m_, mk));
        sE_ += __shfl_xor(sE_, mk);
        sEl_ += __shfl_xor(sEl_, mk);
        s2_ += __shfl_xor(s2_, mk);
        float ob1 = __shfl_xor(a1_, mk); int oj1 = __shfl_xor(i1_, mk);
        float ob2 = __shfl_xor(a2_, mk); int oj2 = __shfl_xor(i2_, mk);
        if (ob1 > a1_ || (ob1 == a1_ && oj1 < i1_)) {
            if (a1_ > ob2 || (a1_ == ob2 && i1_ < oj2)) { a2_ = a1_; i2_ = i1_; }
            else { a2_ = ob2; i2_ = oj2; }
            a1_ = ob1; i1_ = oj1;
        } else {
            if (ob1 > a2_) { a2_ = ob1; i2_ = oj1; }
        }
    }

    __syncthreads();

    if (lane < 16) {
        float* st = &statP[wid][lane][0];
        st[0] = m_; st[1] = sE_; st[2] = sEl_; st[3] = s2_;
        st[4] = a1_; st[5] = __int_as_float(i1_);
        st[6] = a2_; st[7] = __int_as_float(i2_);
    }
    if (wid >= 1) {
        float* scr = scrS + (wid - 1) * 2048;
        #pragma unroll
        for (int df = 0; df < 8; ++df)
            #pragma unroll
            for (int q = 0; q < 4; ++q)
                scr[(kgrp * 4 + q) * 128 + df * 16 + lrow] = accpv[df][q];
    }
    __syncthreads();

    if (wid == 0) {
        if (lane < 16) {
            float M = -1e30f, SE = 0.f, SEL = 0.f, S2 = 0.f;
            float A1 = -1e30f, A2 = -1e30f; int I1 = 0, I2 = 0;
            #pragma unroll
            for (int w = 0; w < 4; ++w) {
                const float* st = &statP[w][lane][0];
                float ob1 = st[4]; int oj1 = __float_as_int(st[5]);
                float ob2 = st[6]; int oj2 = __float_as_int(st[7]);
                M = fmaxf(M, st[0]); SE += st[1]; SEL += st[2]; S2 += st[3];
                if (ob1 > A1 || (ob1 == A1 && oj1 < I1)) {
                    if (A1 > ob2 || (A1 == ob2 && I1 < oj2)) { A2 = A1; I2 = I1; }
                    else { A2 = ob2; I2 = oj2; }
                    A1 = ob1; I1 = oj1;
                } else {
                    if (ob1 > A2) { A2 = ob1; I2 = oj1; }
                }
            }
            int grow = row0 + lane;
            int w_in = inp_word[grow];
            int msk = keyword_table[w_in] != 0;
            out[MASK_OFF + grow] = msk ? 1.0f : 0.0f;
            out[LOGP_OFF + grow] = msk ? M : 0.0f;
            invs2S[lane] = 1.0f / S2;
            mskS[lane] = msk;
            winS[lane] = w_in;
            entS[lane] = msk ? (__logf(SE) - SEL / SE) : 0.0f;
            candS[lane * 2 + 0] = I1;
            candS[lane * 2 + 1] = I2;
        }
        #pragma unroll
        for (int df = 0; df < 8; ++df)
            #pragma unroll
            for (int q = 0; q < 4; ++q)
                accpv[df][q] += scrS[0 * 2048 + (kgrp * 4 + q) * 128 + df * 16 + lrow]
                              + scrS[1 * 2048 + (kgrp * 4 + q) * 128 + df * 16 + lrow]
                              + scrS[2 * 2048 + (kgrp * 4 + q) * 128 + df * 16 + lrow];
    }
    __syncthreads();

    if (wid == 0) {
        #pragma unroll
        for (int df = 0; df < 8; ++df) {
            #pragma unroll
            for (int q = 0; q < 4; ++q) {
                int rl = kgrp * 4 + q;
                int grow = row0 + rl;
                int d = df * 16 + lrow;
                float val = accpv[df][q] * invs2S[rl];
                if (!mskS[rl]) val = W[(size_t)winS[rl] * DD + d];
                out[EMB_OFF + (size_t)grow * DD + d] = val;
            }
        }
    }

    // repair + word/char
    for (int rr = wid; rr < BR; rr += 4) {
        int grow = row0 + rr;
        int i1 = candS[rr * 2 + 0], i2 = candS[rr * 2 + 1];
        int mskr = mskS[rr];
        const float* hrow = hdn + (size_t)grow * HH;
        float4 h0 = *(const float4*)(hrow + lane * 8);
        float4 h1 = *(const float4*)(hrow + lane * 8 + 4);
        float v1, v2;
        {
            const float* wrow = W2Tf + (size_t)i1 * HH;
            float4 w0 = *(const float4*)(wrow + lane * 8);
            float4 w1 = *(const float4*)(wrow + lane * 8 + 4);
            float sdot = h0.x*w0.x + h0.y*w0.y + h0.z*w0.z + h0.w*w0.w
                       + h1.x*w1.x + h1.y*w1.y + h1.z*w1.z + h1.w*w1.w;
            #pragma unroll
            for (int mk = 1; mk < 64; mk <<= 1) sdot += __shfl_xor(sdot, mk);
            v1 = sdot + b2[i1] + gumbel[(size_t)grow * T_NT + i1];
        }
        {
            const float* wrow = W2Tf + (size_t)i2 * HH;
            float4 w0 = *(const float4*)(wrow + lane * 8);
            float4 w1 = *(const float4*)(wrow + lane * 8 + 4);
            float sdot = h0.x*w0.x + h0.y*w0.y + h0.z*w0.z + h0.w*w0.w
                       + h1.x*w1.x + h1.y*w1.y + h1.z*w1.z + h1.w*w1.w;
            #pragma unroll
            for (int mk = 1; mk < 64; mk <<= 1) sdot += __shfl_xor(sdot, mk);
            v2 = sdot + b2[i2] + gumbel[(size_t)grow * T_NT + i2];
        }
        int ibest = (v2 > v1 || (v2 == v1 && i2 < i1)) ? i2 : i1;
        int word = mskr ? tgt_ids[ibest] : winS[rr];
        if (lane == 0) out[WORD_OFF + grow] = (float)word;
        if (lane < MC_)
            out[CHAR_OFF + (size_t)grow * MC_ + lane] = (float)lut[(size_t)word * MC_ + lane];
    }

    if (t == 0) {
        float es = 0.f; int cs = 0;
        #pragma unroll
        for (int r = 0; r < BR; r++) { es += entS[r]; cs += mskS[r]; }
        entP[blockIdx.x] = es;
        cntP[blockIdx.x] = (float)cs;
    }
}

// ---------------- K3 fallback (R14): fused S-MFMA + stats + PV ----------------
__global__ __launch_bounds__(256) void k3_fused_fb(
    const ushort_t* __restrict__ hdnB, const float* __restrict__ hdn,
    const ushort_t* __restrict__ W2q, const float* __restrict__ W2Tf,
    const float* __restrict__ b2, const float* __restrict__ gumbel,
    const int* __restrict__ inp_word, const int* __restrict__ keyword_table,
    const int* __restrict__ tgt_ids, const int* __restrict__ lut,
    const float* __restrict__ W, const ushort_t* __restrict__ wtgtT5,
    float* __restrict__ out, float* __restrict__ entP, float* __restrict__ cntP)
{
    __shared__ float bigS[6144];
    __shared__ float statP[4][16][8];
    __shared__ int   candS[BR * 2];
    __shared__ float invs2S[BR], entS[BR];
    __shared__ int   mskS[BR], winS[BR];

    const int t = threadIdx.x;
    const int wid = t >> 6, lane = t & 63;
    const int lrow = lane & 15, kgrp = lane >> 4;
    const int row0 = blockIdx.x * BR;

    ushort_t* aP = (ushort_t*)bigS;
    #pragma unroll
    for (int it = 0; it < 4; ++it) {
        int gid = it * 256 + t;
        int ks = gid >> 6, l2 = gid & 63;
        int lr = l2 & 15, kg = l2 >> 4;
        uint4 v = *(const uint4*)(hdnB + (size_t)(row0 + lr) * HH + ks * 32 + kg * 8);
        *(uint4*)(aP + gid * 8) = v;
    }
    __syncthreads();

    const int scq = (int)((blockIdx.x + wid) & 3);
    const ushort_t* aRd = aP + lane * 8;
    const float* gRow = gumbel + (size_t)(row0 + lrow) * T_NT + kgrp * 4;

    float m_ = -1e30f, sE_ = 0.f, sEl_ = 0.f, s2_ = 0.f;
    float a1_ = -1e30f, a2_ = -1e30f;
    int i1_ = 0, i2_ = 0;
    f32x4 accpv[8];
    #pragma unroll
    for (int df = 0; df < 8; ++df) accpv[df] = (f32x4){0.f, 0.f, 0.f, 0.f};

    f32x4 ga = *(const f32x4*)(gRow + scq * 32);
    f32x4 gb = *(const f32x4*)(gRow + scq * 32 + 16);

    for (int s = 0; s < SPW; ++s) {
        const int sc = scq + 4 * s;
        const int scn = scq + 4 * ((s + 1) & 15);
        f32x4 gna = *(const f32x4*)(gRow + scn * 32);
        f32x4 gnb = *(const f32x4*)(gRow + scn * 32 + 16);
        f32x4 b2a = *(const f32x4*)(b2 + sc * 32 + kgrp * 4);
        f32x4 b2b = *(const f32x4*)(b2 + sc * 32 + kgrp * 4 + 16);

        const ushort_t* w2a = W2q + (size_t)sc * 16384 + lane * 8;
        f32x4 c0a = (f32x4){0.f,0.f,0.f,0.f}, c0b = c0a, c1a = c0a, c1b = c0a;
        #pragma unroll
        for (int ks = 0; ks < 16; ks += 2) {
            short8v avk0 = *(const short8v*)(aRd + (ks + 0) * 512);
            short8v avk1 = *(const short8v*)(aRd + (ks + 1) * 512);
            c0a = __builtin_amdgcn_mfma_f32_16x16x32_bf16(*(const short8v*)(w2a + (ks+0)*512), avk0, c0a, 0, 0, 0);
            c1a = __builtin_amdgcn_mfma_f32_16x16x32_bf16(*(const short8v*)(w2a + 8192 + (ks+0)*512), avk0, c1a, 0, 0, 0);
            c0b = __builtin_amdgcn_mfma_f32_16x16x32_bf16(*(const short8v*)(w2a + (ks+1)*512), avk1, c0b, 0, 0, 0);
            c1b = __builtin_amdgcn_mfma_f32_16x16x32_bf16(*(const short8v*)(w2a + 8192 + (ks+1)*512), avk1, c1b, 0, 0, 0);
        }
        f32x4 acc0 = c0a + c0b;
        f32x4 acc1 = c1a + c1b;

        const ushort_t* vt = wtgtT5 + (size_t)sc * 4096 + lane * 8;
        short8v bvf[8];
        #pragma unroll
        for (int df = 0; df < 8; ++df) bvf[df] = *(const short8v*)(vt + df * 512);

        short8v pav;
        const int colb = sc * 32 + kgrp * 4;
        #pragma unroll
        for (int q = 0; q < 4; ++q) {
            float l0 = acc0[q] + b2a[q];
            m_ = fmaxf(m_, l0);
            float e0 = __expf(l0);
            sE_ += e0; sEl_ = fmaf(e0, l0, sEl_);
            float aa0 = l0 + ga[q];
            float p0 = __expf(2.0f * aa0);
            s2_ += p0;
            if (aa0 > a1_) { a2_ = a1_; i2_ = i1_; a1_ = aa0; i1_ = colb + q; }
            else if (aa0 > a2_) { a2_ = aa0; i2_ = colb + q; }
            pav[q] = (short)f2bf(p0);
            float l1 = acc1[q] + b2b[q];
            m_ = fmaxf(m_, l1);
            float e1 = __expf(l1);
            sE_ += e1; sEl_ = fmaf(e1, l1, sEl_);
            float aa1 = l1 + gb[q];
            float p1 = __expf(2.0f * aa1);
            s2_ += p1;
            if (aa1 > a1_) { a2_ = a1_; i2_ = i1_; a1_ = aa1; i1_ = colb + 16 + q; }
            else if (aa1 > a2_) { a2_ = aa1; i2_ = colb + 16 + q; }
            pav[4 + q] = (short)f2bf(p1);
        }

        #pragma unroll
        for (int df = 0; df < 8; ++df)
            accpv[df] = __builtin_amdgcn_mfma_f32_16x16x32_bf16(pav, bvf[df], accpv[df], 0, 0, 0);

        ga = gna; gb = gnb;
    }

    #pragma unroll
    for (int mk = 16; mk < 64; mk <<= 1) {
        m_ = fmaxf(m_, __shfl_xor(m_, mk));
        sE_ += __shfl_xor(sE_, mk);
        sEl_ += __shfl_xor(sEl_, mk);
        s2_ += __shfl_xor(s2_, mk);
        float ob1 = __shfl_xor(a1_, mk); int oj1 = __shfl_xor(i1_, mk);
        float ob2 = __shfl_xor(a2_, mk); int oj2 = __shfl_xor(i2_, mk);
        if (ob1 > a1_ || (ob1 == a1_ && oj1 < i1_)) {
            if (a1_ > ob2 || (a1_ == ob2 && i1_ < oj2)) { a2_ = a1_; i2_ = i1_; }
            else { a2_ = ob2; i2_ = oj2; }
            a1_ = ob1; i1_ = oj1;
        } else {
            if (ob1 > a2_) { a2_ = ob1; i2_ = oj1; }
        }
    }

    __syncthreads();

    if (lane < 16) {
        float* st = &statP[wid][lane][0];
        st[0] = m_; st[1] = sE_; st[2] = sEl_; st[3] = s2_;
        st[4] = a1_; st[5] = __int_as_float(i1_);
        st[6] = a2_; st[7] = __int_as_float(i2_);
    }
    if (wid >= 1) {
        float* scr = bigS + (wid - 1) * 2048;
        #pragma unroll
        for (int df = 0; df < 8; ++df)
            #pragma unroll
            for (int q = 0; q < 4; ++q)
                scr[(kgrp * 4 + q) * 128 + df * 16 + lrow] = accpv[df][q];
    }
    __syncthreads();

    if (wid == 0) {
        if (lane < 16) {
            float M = -1e30f, SE = 0.f, SEL = 0.f, S2 = 0.f;
            float A1 = -1e30f, A2 = -1e30f; int I1 = 0, I2 = 0;
            #pragma unroll
            for (int w = 0; w < 4; ++w) {
                const float* st = &statP[w][lane][0];
                float ob1 = st[4]; int oj1 = __float_as_int(st[5]);
                float ob2 = st[6]; int oj2 = __float_as_int(st[7]);
                M = fmaxf(M, st[0]); SE += st[1]; SEL += st[2]; S2 += st[3];
                if (ob1 > A1 || (ob1 == A1 && oj1 < I1)) {
                    if (A1 > ob2 || (A1 == ob2 && I1 < oj2)) { A2 = A1; I2 = I1; }
                    else { A2 = ob2; I2 = oj2; }
                    A1 = ob1; I1 = oj1;
                } else {
                    if (ob1 > A2) { A2 = ob1; I2 = oj1; }
                }
            }
            int grow = row0 + lane;
            int w_in = inp_word[grow];
            int msk = keyword_table[w_in] != 0;
            out[MASK_OFF + grow] = msk ? 1.0f : 0.0f;
            out[LOGP_OFF + grow] = msk ? M : 0.0f;
            invs2S[lane] = 1.0f / S2;
            mskS[lane] = msk;
            winS[lane] = w_in;
            entS[lane] = msk ? (__logf(SE) - SEL / SE) : 0.0f;
            candS[lane * 2 + 0] = I1;
            candS[lane * 2 + 1] = I2;
        }
        #pragma unroll
        for (int df = 0; df < 8; ++df)
            #pragma unroll
            for (int q = 0; q < 4; ++q)
                accpv[df][q] += bigS[0 * 2048 + (kgrp * 4 + q) * 128 + df * 16 + lrow]
                              + bigS[1 * 2048 + (kgrp * 4 + q) * 128 + df * 16 + lrow]
                              + bigS[2 * 2048 + (kgrp * 4 + q) * 128 + df * 16 + lrow];
    }
    __syncthreads();

    if (wid == 0) {
        #pragma unroll
        for (int df = 0; df < 8; ++df) {
            #pragma unroll
            for (int q = 0; q < 4; ++q) {
                int rl = kgrp * 4 + q;
                int grow = row0 + rl;
                int d = df * 16 + lrow;
                float val = accpv[df][q] * invs2S[rl];
                if (!mskS[rl]) val = W[(size_t)winS[rl] * DD + d];
                out[EMB_OFF + (size_t)grow * DD + d] = val;
            }
        }
    }

    for (int rr = wid; rr < BR; rr += 4) {
        int grow = row0 + rr;
        int i1 = candS[rr * 2 + 0], i2 = candS[rr * 2 + 1];
        int mskr = mskS[rr];
        const float* hrow = hdn + (size_t)grow * HH;
        float4 h0 = *(const float4*)(hrow + lane * 8);
        float4 h1 = *(const float4*)(hrow + lane * 8 + 4);
        float v1, v2;
        {
            const float* wrow = W2Tf + (size_t)i1 * HH;
            float4 w0 = *(const float4*)(wrow + lane * 8);
            float4 w1 = *(const float4*)(wrow + lane * 8 + 4);
            float sdot = h0.x*w0.x + h0.y*w0.y + h0.z*w0.z + h0.w*w0.w
                       + h1.x*w1.x + h1.y*w1.y + h1.z*w1.z + h1.w*w1.w;
            #pragma unroll
            for (int mk = 1; mk < 64; mk <<= 1) sdot += __shfl_xor(sdot, mk);
            v1 = sdot + b2[i1] + gumbel[(size_t)grow * T_NT + i1];
        }
        {
            const float* wrow = W2Tf + (size_t)i2 * HH;
            float4 w0 = *(const float4*)(wrow + lane * 8);
            float4 w1 = *(const float4*)(wrow + lane * 8 + 4);
            float sdot = h0.x*w0.x + h0.y*w0.y + h0.z*w0.z + h0.w*w0.w
                       + h1.x*w1.x + h1.y*w1.y + h1.z*w1.z + h1.w*w1.w;
            #pragma unroll
            for (int mk = 1; mk < 64; mk <<= 1) sdot += __shfl_xor(sdot, mk);
            v2 = sdot + b2[i2] + gumbel[(size_t)grow * T_NT + i2];
        }
        int ibest = (v2 > v1 || (v2 == v1 && i2 < i1)) ? i2 : i1;
        int word = mskr ? tgt_ids[ibest] : winS[rr];
        if (lane == 0) out[WORD_OFF + grow] = (float)word;
        if (lane < MC_)
            out[CHAR_OFF + (size_t)grow * MC_ + lane] = (float)lut[(size_t)word * MC_ + lane];
    }

    if (t == 0) {
        float es = 0.f; int cs = 0;
        #pragma unroll
        for (int r = 0; r < BR; r++) { es += entS[r]; cs += mskS[r]; }
        entP[blockIdx.x] = es;
        cntP[blockIdx.x] = (float)cs;
    }
}

// ---------------- K4: final loss reduction ----------------
__global__ __launch_bounds__(256) void k4_loss(
    const float* __restrict__ entP, const float* __restrict__ cntP, float* __restrict__ out)
{
    __shared__ float sE[256], sC[256];
    int t = threadIdx.x;
    float e = 0.f, c = 0.f;
    for (int i = t; i < NBLK; i += 256) { e += entP[i]; c += cntP[i]; }
    sE[t] = e; sC[t] = c;
    __syncthreads();
    for (int s = 128; s > 0; s >>= 1) {
        if (t < s) { sE[t] += sE[t + s]; sC[t] += sC[t + s]; }
        __syncthreads();
    }
    if (t == 0) {
        float ns = fmaxf(sC[0], 1.0f);
        out[LOSS_OFF] = 0.03f * sE[0] / ns;
    }
}

// ---------------- launch ----------------
extern "C" void kernel_launch(void* const* d_in, const int* in_sizes, int n_in,
                              void* d_out, int out_size, void* d_ws, size_t ws_size,
                              hipStream_t stream) {
    const int* inp_word = (const int*)d_in[0];
    const int* keyword_table = (const int*)d_in[3];
    const int* tgt_ids = (const int*)d_in[4];
    const int* lut = (const int*)d_in[5];
    const float* gumbel = (const float*)d_in[6];
    const float* W = (const float*)d_in[7];
    const float* W1 = (const float*)d_in[8];
    const float* b1 = (const float*)d_in[9];
    const float* W2 = (const float*)d_in[10];
    const float* b2 = (const float*)d_in[11];
    float* out = (float*)d_out;

    float* wsf = (float*)d_ws;
    float* hdn = wsf + HDN_OFF;
    ushort_t* hdnB = (ushort_t*)(wsf + HDNB_OFF);
    float* W2Tf = wsf + W2T_OFF;
    ushort_t* W2q = (ushort_t*)(wsf + W2Q_OFF);
    ushort_t* wtgtT5 = (ushort_t*)(wsf + WTT5_OFF);
    float* wtgt = wsf + WT_OFF;
    float* entP = wsf + ENT_OFF;
    float* cntP = wsf + CNT_OFF;
    ushort_t* S = (ushort_t*)(wsf + S_OFF);

    k1_gather<<<T_NT / 2, 256, 0, stream>>>(tgt_ids, W, wtgt);
    k1b_wtgtT5<<<64, 256, 0, stream>>>(wtgt, wtgtT5);
    k0_w2t<<<dim3(T_NT / 32, HH / 32), 256, 0, stream>>>(W2, W2Tf, W2q);
    k2_hdn<<<dim3(R_TOT / 64, HH / 64), 256, 0, stream>>>(inp_word, W, W1, b1, hdn, hdnB);

    if (ws_size >= (size_t)WS_NEED_FLOATS * sizeof(float)) {
        k3a_gemm<<<dim3(16, 256), 256, 0, stream>>>(hdnB, W2q, S);
        k3b_stream<<<NBLK, 256, 0, stream>>>(S, hdn, W2Tf, b2, gumbel,
                                             inp_word, keyword_table, tgt_ids, lut,
                                             W, wtgtT5, out, entP, cntP);
    } else {
        k3_fused_fb<<<NBLK, 256, 0, stream>>>(hdnB, hdn, W2q, W2Tf, b2, gumbel,
                                              inp_word, keyword_table, tgt_ids, lut,
                                              W, wtgtT5, out, entP, cntP);
    }
    k4_loss<<<1, 256, 0, stream>>>(entP, cntP, out);
}

// Round 19
// 249.893 us; speedup vs baseline: 1.1170x; 1.1170x over previous
//
#include <hip/hip_runtime.h>
#include <cstdint>

#define R_TOT 16384
#define T_NT  2048
#define DD    128
#define HH    512
#define MC_   20
#define BR    16             // rows per block in k3b / fallback k3
#define NBLK  1024           // R_TOT / BR
#define SPW   16             // 32-col steps per wave (64 total / 4 waves)

// Output layout (floats)
#define MASK_OFF 0
#define LOGP_OFF 16384
#define WORD_OFF 32768
#define CHAR_OFF 49152
#define EMB_OFF  376832          // 49152 + 16384*20
#define LOSS_OFF 2473984         // 376832 + 16384*128

// ws layout (float slots)
#define HDN_OFF   0              // hdn f32 [16384][512]            (8,388,608)
#define HDNB_OFF  8388608        // hdnB ushort[16384*512]          (4,194,304 slots)
#define W2T_OFF   12582912       // W2Tf f32 [2048][512]            (1,048,576)
#define W2Q_OFF   13631488       // W2q ushort[128cc][16ks][512]    (524,288 slots)
#define WTT5_OFF  14155776       // wtgtT5 ushort[64][8][512]       (131,072 slots)
#define WT_OFF    14286848       // wtgt f32 temp; then invs2_g[16384]
#define ENT_OFF   14548992       // 1024
#define CNT_OFF   14550016       // 1024
#define S_OFF     14551040       // S bf16 ushort[16384*2048]; overwritten with Pn by k3b
#define WS_NEED_FLOATS (S_OFF + 16777216)

typedef __attribute__((ext_vector_type(8))) short short8v;
typedef __attribute__((ext_vector_type(4))) float f32x4;
typedef unsigned short ushort_t;

__device__ __forceinline__ ushort_t f2bf(float f) {
    union { float f; unsigned int u; } v; v.f = f;
    unsigned int r = v.u + 0x7FFFu + ((v.u >> 16) & 1u);
    return (ushort_t)(r >> 16);
}
__device__ __forceinline__ float bf2f(ushort_t u) {
    union { unsigned int u; float f; } v; v.u = ((unsigned int)u) << 16;
    return v.f;
}
__device__ __forceinline__ void stage16(const ushort_t* gsrc, ushort_t* ldst) {
    __builtin_amdgcn_global_load_lds(
        (const __attribute__((address_space(1))) unsigned int*)gsrc,
        (__attribute__((address_space(3))) unsigned int*)ldst, 16, 0, 0);
}

// ---------------- K1: gather wtgt embeddings ----------------
__global__ __launch_bounds__(256) void k1_gather(
    const int* __restrict__ tgt_ids, const float* __restrict__ W, float* __restrict__ wtgt)
{
    int rr = blockIdx.x * 2 + (threadIdx.x >> 7);
    int d = threadIdx.x & 127;
    int wsrc = tgt_ids[rr];
    wtgt[(size_t)rr * DD + d] = W[(size_t)wsrc * DD + d];
}

// ---------------- K1b: wtgt -> wtgtT5 full-K PV B-fragment pack ----------------
__global__ __launch_bounds__(256) void k1b_wtgtT5(
    const float* __restrict__ wtgt, ushort_t* __restrict__ wtgtT5)
{
    const int sc = blockIdx.x, t = threadIdx.x;
    #pragma unroll
    for (int it = 0; it < 2; ++it) {
        int idx = it * 256 + t;
        int df = idx >> 6, lane = idx & 63;
        int lrow = lane & 15, kg = lane >> 4;
        ushort_t* dst = wtgtT5 + ((size_t)sc * 8 + df) * 512 + lane * 8;
        #pragma unroll
        for (int j = 0; j < 8; ++j) {
            int col = sc * 32 + (j < 4 ? kg * 4 + j : 16 + kg * 4 + (j - 4));
            dst[j] = f2bf(wtgt[(size_t)col * DD + df * 16 + lrow]);
        }
    }
}

// ---------------- K0: W2 -> W2Tf f32 + W2q lane-linear fragment pack ----------------
__global__ __launch_bounds__(256) void k0_w2t(
    const float* __restrict__ W2, float* __restrict__ W2Tf, ushort_t* __restrict__ W2q)
{
    __shared__ float tile[32][33];
    const int js = blockIdx.x, ks = blockIdx.y;
    const int cb = js * 32, kb = ks * 32;
    const int lx = threadIdx.x & 31, ly = threadIdx.x >> 5;
    #pragma unroll
    for (int i = 0; i < 32; i += 8)
        tile[ly + i][lx] = W2[(size_t)(kb + ly + i) * T_NT + cb + lx];
    __syncthreads();
    #pragma unroll
    for (int i = 0; i < 32; i += 8) {
        int c = cb + ly + i, k = kb + lx;
        W2Tf[(size_t)c * HH + k] = tile[lx][ly + i];
    }
    if (threadIdx.x < 128) {
        int c = threadIdx.x >> 2, kgrp = threadIdx.x & 3;
        int cs = c >> 4, lrow = c & 15;
        ushort_t* dst = W2q + (size_t)(((js * 2 + cs) * 16 + ks) * 512) + (kgrp * 16 + lrow) * 8;
        #pragma unroll
        for (int i = 0; i < 8; ++i)
            dst[i] = f2bf(tile[kgrp * 8 + i][c]);
    }
}

// ---------------- K2: hdn = relu(W[inp_word] @ W1 + b1), fp32 + bf16 ----------------
__global__ __launch_bounds__(256) void k2_hdn(
    const int* __restrict__ inp_word, const float* __restrict__ W,
    const float* __restrict__ W1, const float* __restrict__ b1,
    float* __restrict__ hdn, ushort_t* __restrict__ hdnB)
{
    __shared__ float As[16][64];
    __shared__ float Bs[16][64];
    const int t = threadIdx.x;
    const int bm = blockIdx.x * 64;
    const int bn = blockIdx.y * 64;
    const int tx = t & 15, ty = t >> 4;
    float acc[4][4] = {};
    for (int k0 = 0; k0 < DD; k0 += 16) {
        {
            int m = t >> 2, kq = t & 3;
            int wsrc = inp_word[bm + m];
            float4 v = *(const float4*)(W + (size_t)wsrc * DD + k0 + kq * 4);
            As[kq * 4 + 0][m] = v.x; As[kq * 4 + 1][m] = v.y;
            As[kq * 4 + 2][m] = v.z; As[kq * 4 + 3][m] = v.w;
        }
        {
            int k = t >> 4, nq = t & 15;
            *(float4*)(&Bs[k][nq * 4]) =
                *(const float4*)(W1 + (size_t)(k0 + k) * HH + bn + nq * 4);
        }
        __syncthreads();
        #pragma unroll
        for (int k = 0; k < 16; ++k) {
            float a[4], b[4];
            #pragma unroll
            for (int i = 0; i < 4; i++) a[i] = As[k][ty * 4 + i];
            #pragma unroll
            for (int j = 0; j < 4; j++) b[j] = Bs[k][tx * 4 + j];
            #pragma unroll
            for (int i = 0; i < 4; i++)
                #pragma unroll
                for (int j = 0; j < 4; j++)
                    acc[i][j] = fmaf(a[i], b[j], acc[i][j]);
        }
        __syncthreads();
    }
    #pragma unroll
    for (int i = 0; i < 4; i++) {
        int m = bm + ty * 4 + i;
        int n = bn + tx * 4;
        float4 v;
        v.x = fmaxf(acc[i][0] + b1[n + 0], 0.f);
        v.y = fmaxf(acc[i][1] + b1[n + 1], 0.f);
        v.z = fmaxf(acc[i][2] + b1[n + 2], 0.f);
        v.w = fmaxf(acc[i][3] + b1[n + 3], 0.f);
        *(float4*)(hdn + (size_t)m * HH + n) = v;
        ushort4 hb;
        hb.x = f2bf(v.x); hb.y = f2bf(v.y); hb.z = f2bf(v.z); hb.w = f2bf(v.w);
        *(ushort4*)(hdnB + (size_t)m * HH + n) = hb;
    }
}

// ---------------- K3a: m97-style staged GEMM S = hdn @ W2 (bf16 out) ----------------
// grid (nb 16, mb 128), 256 thr = 4 waves (wr=wid>>1, wc=wid&1), 128x128 tile, BK=32.
// Double-buffered LDS (A 8KB + B 8KB per buf = 32KB), global_load_lds staging,
// lane-linear 1KB-granule reads (conflict-free), 16 independent acc chains.
__global__ __launch_bounds__(256) void k3a_gemm(
    const ushort_t* __restrict__ hdnB, const ushort_t* __restrict__ W2q,
    ushort_t* __restrict__ S)
{
    __shared__ ushort_t aT[2 * 4096];
    __shared__ ushort_t bT[2 * 4096];

    const int t = threadIdx.x;
    const int wid = t >> 6, lane = t & 63;
    const int lrow = lane & 15, kgrp = lane >> 4;
    const int nb = blockIdx.x, mb = blockIdx.y;
    const int wr = wid >> 1, wc = wid & 1;

    f32x4 acc[4][4];
    #pragma unroll
    for (int r = 0; r < 4; ++r)
        #pragma unroll
        for (int c = 0; c < 4; ++c) acc[r][c] = (f32x4){0.f, 0.f, 0.f, 0.f};

    // stage K-step ks into buffer buf: wave wid stages A granules {wid*2, wid*2+1}
    // and B granules {wid*2, wid*2+1} (1KB each, 2 stage16/lane each).
    #define K3A_STAGE(buf, ks)                                                          \
        {                                                                               \
            _Pragma("unroll")                                                           \
            for (int i = 0; i < 2; ++i) {                                               \
                int g = wid * 2 + i;                                                    \
                const ushort_t* asrc = hdnB + (size_t)(mb * 128 + g * 16 + lrow) * HH   \
                                       + (ks) * 32 + kgrp * 8;                          \
                stage16(asrc, &aT[(buf) * 4096 + g * 512 + lane * 8]);                  \
                const ushort_t* bsrc = W2q + (size_t)(((nb * 8 + g) * 16 + (ks)) * 512) \
                                       + lane * 8;                                      \
                stage16(bsrc, &bT[(buf) * 4096 + g * 512 + lane * 8]);                  \
            }                                                                           \
        }

    K3A_STAGE(0, 0);
    __syncthreads();

    for (int ks = 0; ks < 16; ++ks) {
        const int buf = ks & 1;
        if (ks + 1 < 16) K3A_STAGE(buf ^ 1, ks + 1);

        short8v af[4], bf[4];
        #pragma unroll
        for (int r = 0; r < 4; ++r)
            af[r] = *(const short8v*)&aT[buf * 4096 + (wr * 4 + r) * 512 + lane * 8];
        #pragma unroll
        for (int c = 0; c < 4; ++c)
            bf[c] = *(const short8v*)&bT[buf * 4096 + (wc * 4 + c) * 512 + lane * 8];

        #pragma unroll
        for (int r = 0; r < 4; ++r)
            #pragma unroll
            for (int c = 0; c < 4; ++c)
                acc[r][c] = __builtin_amdgcn_mfma_f32_16x16x32_bf16(bf[c], af[r], acc[r][c], 0, 0, 0);

        __syncthreads();
    }

    // store: lane holds S[mb*128 + wr*64 + r*16 + lrow][nb*128 + wc*64 + c*16 + kgrp*4 + q]
    #pragma unroll
    for (int r = 0; r < 4; ++r) {
        #pragma unroll
        for (int c = 0; c < 4; ++c) {
            int row = mb * 128 + wr * 64 + r * 16 + lrow;
            int col = nb * 128 + wc * 64 + c * 16 + kgrp * 4;
            ushort4 o;
            o.x = f2bf(acc[r][c][0]); o.y = f2bf(acc[r][c][1]);
            o.z = f2bf(acc[r][c][2]); o.w = f2bf(acc[r][c][3]);
            *(ushort4*)(S + (size_t)row * T_NT + col) = o;
        }
    }
    #undef K3A_STAGE
}

// ---------------- K3b: streaming stats over S; writes Pn (in-place) + invs2 ----------------
// 1024 blocks x 16 rows, 4 independent col-stream waves, no in-loop barriers, no MFMA.
__global__ __launch_bounds__(256) void k3b_stream(
    ushort_t* __restrict__ S, const float* __restrict__ hdn,
    const float* __restrict__ W2Tf, const float* __restrict__ b2,
    const float* __restrict__ gumbel, const int* __restrict__ inp_word,
    const int* __restrict__ keyword_table, const int* __restrict__ tgt_ids,
    const int* __restrict__ lut, float* __restrict__ invs2_g,
    float* __restrict__ out, float* __restrict__ entP, float* __restrict__ cntP)
{
    __shared__ float statP[4][16][8];
    __shared__ int   candS[BR * 2];
    __shared__ float entS[BR];
    __shared__ int   mskS[BR], winS[BR];

    const int t = threadIdx.x;
    const int wid = t >> 6, lane = t & 63;
    const int lrow = lane & 15, kgrp = lane >> 4;
    const int row0 = blockIdx.x * BR;
    const int scq = (int)((blockIdx.x + wid) & 3);

    ushort_t* sRow = S + (size_t)(row0 + lrow) * T_NT + kgrp * 4;
    const float* gRow = gumbel + (size_t)(row0 + lrow) * T_NT + kgrp * 4;

    float m_ = -1e30f, sE_ = 0.f, sEl_ = 0.f, s2_ = 0.f;
    float a1_ = -1e30f, a2_ = -1e30f;
    int i1_ = 0, i2_ = 0;

    ushort4 sa = *(const ushort4*)(sRow + scq * 32);
    ushort4 sb = *(const ushort4*)(sRow + scq * 32 + 16);
    f32x4 ga = *(const f32x4*)(gRow + scq * 32);
    f32x4 gb = *(const f32x4*)(gRow + scq * 32 + 16);

    for (int s = 0; s < SPW; ++s) {
        const int sc = scq + 4 * s;
        const int scn = scq + 4 * ((s + 1) & 15);

        ushort4 san = *(const ushort4*)(sRow + scn * 32);
        ushort4 sbn = *(const ushort4*)(sRow + scn * 32 + 16);
        f32x4 gna = *(const f32x4*)(gRow + scn * 32);
        f32x4 gnb = *(const f32x4*)(gRow + scn * 32 + 16);

        f32x4 b2a = *(const f32x4*)(b2 + sc * 32 + kgrp * 4);
        f32x4 b2b = *(const f32x4*)(b2 + sc * 32 + kgrp * 4 + 16);

        ushort_t sa_[4] = {sa.x, sa.y, sa.z, sa.w};
        ushort_t sb_[4] = {sb.x, sb.y, sb.z, sb.w};
        ushort_t pa_[4], pb_[4];

        const int colb = sc * 32 + kgrp * 4;
        #pragma unroll
        for (int q = 0; q < 4; ++q) {
            float l0 = bf2f(sa_[q]) + b2a[q];
            m_ = fmaxf(m_, l0);
            float e0 = __expf(l0);
            sE_ += e0; sEl_ = fmaf(e0, l0, sEl_);
            float aa0 = l0 + ga[q];
            float p0 = __expf(2.0f * aa0);
            s2_ += p0;
            if (aa0 > a1_) { a2_ = a1_; i2_ = i1_; a1_ = aa0; i1_ = colb + q; }
            else if (aa0 > a2_) { a2_ = aa0; i2_ = colb + q; }
            pa_[q] = f2bf(p0);

            float l1 = bf2f(sb_[q]) + b2b[q];
            m_ = fmaxf(m_, l1);
            float e1 = __expf(l1);
            sE_ += e1; sEl_ = fmaf(e1, l1, sEl_);
            float aa1 = l1 + gb[q];
            float p1 = __expf(2.0f * aa1);
            s2_ += p1;
            if (aa1 > a1_) { a2_ = a1_; i2_ = i1_; a1_ = aa1; i1_ = colb + 16 + q; }
            else if (aa1 > a2_) { a2_ = aa1; i2_ = colb + 16 + q; }
            pb_[q] = f2bf(p1);
        }
        // write Pn over S (same elements this lane just read)
        ushort4 pa4 = make_ushort4(pa_[0], pa_[1], pa_[2], pa_[3]);
        ushort4 pb4 = make_ushort4(pb_[0], pb_[1], pb_[2], pb_[3]);
        *(ushort4*)(sRow + sc * 32) = pa4;
        *(ushort4*)(sRow + sc * 32 + 16) = pb4;

        sa = san; sb = sbn; ga = gna; gb = gnb;
    }

    // in-wave reduction across kgrp
    #pragma unroll
    for (int mk = 16; mk < 64; mk <<= 1) {
        m_ = fmaxf(m_, __shfl_xor(m_, mk));
        sE_ += __shfl_xor(sE_, mk);
        sEl_ += __shfl_xor(sEl_, mk);
        s2_ += __shfl_xor(s2_, mk);
        float ob1 = __shfl_xor(a1_, mk); int oj1 = __shfl_xor(i1_, mk);
        float ob2 = __shfl_xor(a2_, mk); int oj2 = __shfl_xor(i2_, mk);
        if (ob1 > a1_ || (ob1 == a1_ && oj1 < i1_)) {
            if (a1_ > ob2 || (a1_ == ob2 && i1_ < oj2)) { a2_ = a1_; i2_ = i1_; }
            else { a2_ = ob2; i2_ = oj2; }
            a1_ = ob1; i1_ = oj1;
        } else {
            if (ob1 > a2_) { a2_ = ob1; i2_ = oj1; }
        }
    }

    __syncthreads();
    if (lane < 16) {
        float* st = &statP[wid][lane][0];
        st[0] = m_; st[1] = sE_; st[2] = sEl_; st[3] = s2_;
        st[4] = a1_; st[5] = __int_as_float(i1_);
        st[6] = a2_; st[7] = __int_as_float(i2_);
    }
    __syncthreads();

    if (wid == 0 && lane < 16) {
        float M = -1e30f, SE = 0.f, SEL = 0.f, S2 = 0.f;
        float A1 = -1e30f, A2 = -1e30f; int I1 = 0, I2 = 0;
        #pragma unroll
        for (int w = 0; w < 4; ++w) {
            const float* st = &statP[w][lane][0];
            float ob1 = st[4]; int oj1 = __float_as_int(st[5]);
            float ob2 = st[6]; int oj2 = __float_as_int(st[7]);
            M = fmaxf(M, st[0]); SE += st[1]; SEL += st[2]; S2 += st[3];
            if (ob1 > A1 || (ob1 == A1 && oj1 < I1)) {
                if (A1 > ob2 || (A1 == ob2 && I1 < oj2)) { A2 = A1; I2 = I1; }
                else { A2 = ob2; I2 = oj2; }
                A1 = ob1; I1 = oj1;
            } else {
                if (ob1 > A2) { A2 = ob1; I2 = oj1; }
            }
        }
        int grow = row0 + lane;
        int w_in = inp_word[grow];
        int msk = keyword_table[w_in] != 0;
        out[MASK_OFF + grow] = msk ? 1.0f : 0.0f;
        out[LOGP_OFF + grow] = msk ? M : 0.0f;
        invs2_g[grow] = 1.0f / S2;
        mskS[lane] = msk;
        winS[lane] = w_in;
        entS[lane] = msk ? (__logf(SE) - SEL / SE) : 0.0f;
        candS[lane * 2 + 0] = I1;
        candS[lane * 2 + 1] = I2;
    }
    __syncthreads();

    // repair + word/char
    for (int rr = wid; rr < BR; rr += 4) {
        int grow = row0 + rr;
        int i1 = candS[rr * 2 + 0], i2 = candS[rr * 2 + 1];
        int mskr = mskS[rr];
        const float* hrow = hdn + (size_t)grow * HH;
        float4 h0 = *(const float4*)(hrow + lane * 8);
        float4 h1 = *(const float4*)(hrow + lane * 8 + 4);
        float v1, v2;
        {
            const float* wrow = W2Tf + (size_t)i1 * HH;
            float4 w0 = *(const float4*)(wrow + lane * 8);
            float4 w1 = *(const float4*)(wrow + lane * 8 + 4);
            float sdot = h0.x*w0.x + h0.y*w0.y + h0.z*w0.z + h0.w*w0.w
                       + h1.x*w1.x + h1.y*w1.y + h1.z*w1.z + h1.w*w1.w;
            #pragma unroll
            for (int mk = 1; mk < 64; mk <<= 1) sdot += __shfl_xor(sdot, mk);
            v1 = sdot + b2[i1] + gumbel[(size_t)grow * T_NT + i1];
        }
        {
            const float* wrow = W2Tf + (size_t)i2 * HH;
            float4 w0 = *(const float4*)(wrow + lane * 8);
            float4 w1 = *(const float4*)(wrow + lane * 8 + 4);
            float sdot = h0.x*w0.x + h0.y*w0.y + h0.z*w0.z + h0.w*w0.w
                       + h1.x*w1.x + h1.y*w1.y + h1.z*w1.z + h1.w*w1.w;
            #pragma unroll
            for (int mk = 1; mk < 64; mk <<= 1) sdot += __shfl_xor(sdot, mk);
            v2 = sdot + b2[i2] + gumbel[(size_t)grow * T_NT + i2];
        }
        int ibest = (v2 > v1 || (v2 == v1 && i2 < i1)) ? i2 : i1;
        int word = mskr ? tgt_ids[ibest] : winS[rr];
        if (lane == 0) out[WORD_OFF + grow] = (float)word;
        if (lane < MC_)
            out[CHAR_OFF + (size_t)grow * MC_ + lane] = (float)lut[(size_t)word * MC_ + lane];
    }

    if (t == 0) {
        float es = 0.f; int cs = 0;
        #pragma unroll
        for (int r = 0; r < BR; r++) { es += entS[r]; cs += mskS[r]; }
        entP[blockIdx.x] = es;
        cntP[blockIdx.x] = (float)cs;
    }
}

// ---------------- K3c: x_emb = (Pn @ wtgt) * invs2, masked select ----------------
// grid 512 blocks x 256 thr = 4 waves (row-half x col-half). BM=32, K=2048.
__global__ __launch_bounds__(256) void k3c_pv(
    const ushort_t* __restrict__ Pn, const ushort_t* __restrict__ wtgtT5,
    const float* __restrict__ invs2_g, const int* __restrict__ inp_word,
    const int* __restrict__ keyword_table, const float* __restrict__ W,
    float* __restrict__ out)
{
    const int t = threadIdx.x;
    const int wid = t >> 6, lane = t & 63;
    const int lrow = lane & 15, kgrp = lane >> 4;
    const int rbase = blockIdx.x * 32 + (wid >> 1) * 16;
    const int ch = wid & 1;

    const ushort_t* pRow = Pn + (size_t)(rbase + lrow) * T_NT + kgrp * 4;
    const ushort_t* vBase = wtgtT5 + (size_t)(ch * 4) * 512 + lane * 8;

    f32x4 acc[4];
    #pragma unroll
    for (int df = 0; df < 4; ++df) acc[df] = (f32x4){0.f, 0.f, 0.f, 0.f};

    for (int sc = 0; sc < 64; ++sc) {
        ushort4 pa = *(const ushort4*)(pRow + sc * 32);
        ushort4 pb = *(const ushort4*)(pRow + sc * 32 + 16);
        short8v pav;
        pav[0] = (short)pa.x; pav[1] = (short)pa.y; pav[2] = (short)pa.z; pav[3] = (short)pa.w;
        pav[4] = (short)pb.x; pav[5] = (short)pb.y; pav[6] = (short)pb.z; pav[7] = (short)pb.w;
        const ushort_t* vt = vBase + (size_t)sc * 4096;
        #pragma unroll
        for (int df = 0; df < 4; ++df) {
            short8v bv = *(const short8v*)(vt + df * 512);
            acc[df] = __builtin_amdgcn_mfma_f32_16x16x32_bf16(pav, bv, acc[df], 0, 0, 0);
        }
    }

    // epilogue: lane holds x_emb[rbase + kgrp*4 + q][ch*64 + df*16 + lrow]
    #pragma unroll
    for (int q = 0; q < 4; ++q) {
        int row = rbase + kgrp * 4 + q;
        int w_in = inp_word[row];
        int msk = keyword_table[w_in] != 0;
        float inv = invs2_g[row];
        #pragma unroll
        for (int df = 0; df < 4; ++df) {
            int d = ch * 64 + df * 16 + lrow;
            float val = msk ? acc[df][q] * inv : W[(size_t)w_in * DD + d];
            out[EMB_OFF + (size_t)row * DD + d] = val;
        }
    }
}

// ---------------- K3 fallback (R14-best): fused S-MFMA + stats + PV ----------------
__global__ __launch_bounds__(256) void k3_fused_fb(
    const ushort_t* __restrict__ hdnB, const float* __restrict__ hdn,
    const ushort_t* __restrict__ W2q, const float* __restrict__ W2Tf,
    const float* __restrict__ b2, const float* __restrict__ gumbel,
    const int* __restrict__ inp_word, const int* __restrict__ keyword_table,
    const int* __restrict__ tgt_ids, const int* __restrict__ lut,
    const float* __restrict__ W, const ushort_t* __restrict__ wtgtT5,
    float* __restrict__ out, float* __restrict__ entP, float* __restrict__ cntP)
{
    __shared__ float bigS[6144];
    __shared__ float statP[4][16][8];
    __shared__ int   candS[BR * 2];
    __shared__ float invs2S[BR], entS[BR];
    __shared__ int   mskS[BR], winS[BR];

    const int t = threadIdx.x;
    const int wid = t >> 6, lane = t & 63;
    const int lrow = lane & 15, kgrp = lane >> 4;
    const int row0 = blockIdx.x * BR;

    ushort_t* aP = (ushort_t*)bigS;
    #pragma unroll
    for (int it = 0; it < 4; ++it) {
        int gid = it * 256 + t;
        int ks = gid >> 6, l2 = gid & 63;
        int lr = l2 & 15, kg = l2 >> 4;
        uint4 v = *(const uint4*)(hdnB + (size_t)(row0 + lr) * HH + ks * 32 + kg * 8);
        *(uint4*)(aP + gid * 8) = v;
    }
    __syncthreads();

    const int scq = (int)((blockIdx.x + wid) & 3);
    const ushort_t* aRd = aP + lane * 8;
    const float* gRow = gumbel + (size_t)(row0 + lrow) * T_NT + kgrp * 4;

    float m_ = -1e30f, sE_ = 0.f, sEl_ = 0.f, s2_ = 0.f;
    float a1_ = -1e30f, a2_ = -1e30f;
    int i1_ = 0, i2_ = 0;
    f32x4 accpv[8];
    #pragma unroll
    for (int df = 0; df < 8; ++df) accpv[df] = (f32x4){0.f, 0.f, 0.f, 0.f};

    f32x4 ga = *(const f32x4*)(gRow + scq * 32);
    f32x4 gb = *(const f32x4*)(gRow + scq * 32 + 16);

    for (int s = 0; s < SPW; ++s) {
        const int sc = scq + 4 * s;
        const int scn = scq + 4 * ((s + 1) & 15);
        f32x4 gna = *(const f32x4*)(gRow + scn * 32);
        f32x4 gnb = *(const f32x4*)(gRow + scn * 32 + 16);
        f32x4 b2a = *(const f32x4*)(b2 + sc * 32 + kgrp * 4);
        f32x4 b2b = *(const f32x4*)(b2 + sc * 32 + kgrp * 4 + 16);

        const ushort_t* w2a = W2q + (size_t)sc * 16384 + lane * 8;
        f32x4 c0a = (f32x4){0.f,0.f,0.f,0.f}, c0b = c0a, c1a = c0a, c1b = c0a;
        #pragma unroll
        for (int ks = 0; ks < 16; ks += 2) {
            short8v avk0 = *(const short8v*)(aRd + (ks + 0) * 512);
            short8v avk1 = *(const short8v*)(aRd + (ks + 1) * 512);
            c0a = __builtin_amdgcn_mfma_f32_16x16x32_bf16(*(const short8v*)(w2a + (ks+0)*512), avk0, c0a, 0, 0, 0);
            c1a = __builtin_amdgcn_mfma_f32_16x16x32_bf16(*(const short8v*)(w2a + 8192 + (ks+0)*512), avk0, c1a, 0, 0, 0);
            c0b = __builtin_amdgcn_mfma_f32_16x16x32_bf16(*(const short8v*)(w2a + (ks+1)*512), avk1, c0b, 0, 0, 0);
            c1b = __builtin_amdgcn_mfma_f32_16x16x32_bf16(*(const short8v*)(w2a + 8192 + (ks+1)*512), avk1, c1b, 0, 0, 0);
        }
        f32x4 acc0 = c0a + c0b;
        f32x4 acc1 = c1a + c1b;

        const ushort_t* vt = wtgtT5 + (size_t)sc * 4096 + lane * 8;
        short8v bvf[8];
        #pragma unroll
        for (int df = 0; df < 8; ++df) bvf[df] = *(const short8v*)(vt + df * 512);

        short8v pav;
        const int colb = sc * 32 + kgrp * 4;
        #pragma unroll
        for (int q = 0; q < 4; ++q) {
            float l0 = acc0[q] + b2a[q];
            m_ = fmaxf(m_, l0);
            float e0 = __expf(l0);
            sE_ += e0; sEl_ = fmaf(e0, l0, sEl_);
            float aa0 = l0 + ga[q];
            float p0 = __expf(2.0f * aa0);
            s2_ += p0;
            if (aa0 > a1_) { a2_ = a1_; i2_ = i1_; a1_ = aa0; i1_ = colb + q; }
            else if (aa0 > a2_) { a2_ = aa0; i2_ = colb + q; }
            pav[q] = (short)f2bf(p0);
            float l1 = acc1[q] + b2b[q];
            m_ = fmaxf(m_, l1);
            float e1 = __expf(l1);
            sE_ += e1; sEl_ = fmaf(e1, l1, sEl_);
            float aa1 = l1 + gb[q];
            float p1 = __expf(2.0f * aa1);
            s2_ += p1;
            if (aa1 > a1_) { a2_ = a1_; i2_ = i1_; a1_ = aa1; i1_ = colb + 16 + q; }
            else if (aa1 > a2_) { a2_ = aa1; i2_ = colb + 16 + q; }
            pav[4 + q] = (short)f2bf(p1);
        }

        #pragma unroll
        for (int df = 0; df < 8; ++df)
            accpv[df] = __builtin_amdgcn_mfma_f32_16x16x32_bf16(pav, bvf[df], accpv[df], 0, 0, 0);

        ga = gna; gb = gnb;
    }

    #pragma unroll
    for (int mk = 16; mk < 64; mk <<= 1) {
        m_ = fmaxf(m_, __shfl_xor(m_, mk));
        sE_ += __shfl_xor(sE_, mk);
        sEl_ += __shfl_xor(sEl_, mk);
        s2_ += __shfl_xor(s2_, mk);
        float ob1 = __shfl_xor(a1_, mk); int oj1 = __shfl_xor(i1_, mk);
        float ob2 = __shfl_xor(a2_, mk); int oj2 = __shfl_xor(i2_, mk);
        if (ob1 > a1_ || (ob1 == a1_ && oj1 < i1_)) {
            if (a1_ > ob2 || (a1_ == ob2 && i1_ < oj2)) { a2_ = a1_; i2_ = i1_; }
            else { a2_ = ob2; i2_ = oj2; }
            a1_ = ob1; i1_ = oj1;
        } else {
            if (ob1 > a2_) { a2_ = ob1; i2_ = oj1; }
        }
    }

    __syncthreads();
    if (lane < 16) {
        float* st = &statP[wid][lane][0];
        st[0] = m_; st[1] = sE_; st[2] = sEl_; st[3] = s2_;
        st[4] = a1_; st[5] = __int_as_float(i1_);
        st[6] = a2_; st[7] = __int_as_float(i2_);
    }
    if (wid >= 1) {
        float* scr = bigS + (wid - 1) * 2048;
        #pragma unroll
        for (int df = 0; df < 8; ++df)
            #pragma unroll
            for (int q = 0; q < 4; ++q)
                scr[(kgrp * 4 + q) * 128 + df * 16 + lrow] = accpv[df][q];
    }
    __syncthreads();

    if (wid == 0) {
        if (lane < 16) {
            float M = -1e30f, SE = 0.f, SEL = 0.f, S2 = 0.f;
            float A1 = -1e30f, A2 = -1e30f; int I1 = 0, I2 = 0;
            #pragma unroll
            for (int w = 0; w < 4; ++w) {
                const float* st = &statP[w][lane][0];
                float ob1 = st[4]; int oj1 = __float_as_int(st[5]);
                float ob2 = st[6]; int oj2 = __float_as_int(st[7]);
                M = fmaxf(M, st[0]); SE += st[1]; SEL += st[2]; S2 += st[3];
                if (ob1 > A1 || (ob1 == A1 && oj1 < I1)) {
                    if (A1 > ob2 || (A1 == ob2 && I1 < oj2)) { A2 = A1; I2 = I1; }
                    else { A2 = ob2; I2 = oj2; }
                    A1 = ob1; I1 = oj1;
                } else {
                    if (ob1 > A2) { A2 = ob1; I2 = oj1; }
                }
            }
            int grow = row0 + lane;
            int w_in = inp_word[grow];
            int msk = keyword_table[w_in] != 0;
            out[MASK_OFF + grow] = msk ? 1.0f : 0.0f;
            out[LOGP_OFF + grow] = msk ? M : 0.0f;
            invs2S[lane] = 1.0f / S2;
            mskS[lane] = msk;
            winS[lane] = w_in;
            entS[lane] = msk ? (__logf(SE) - SEL / SE) : 0.0f;
            candS[lane * 2 + 0] = I1;
            candS[lane * 2 + 1] = I2;
        }
        #pragma unroll
        for (int df = 0; df < 8; ++df)
            #pragma unroll
            for (int q = 0; q < 4; ++q)
                accpv[df][q] += bigS[0 * 2048 + (kgrp * 4 + q) * 128 + df * 16 + lrow]
                              + bigS[1 * 2048 + (kgrp * 4 + q) * 128 + df * 16 + lrow]
                              + bigS[2 * 2048 + (kgrp * 4 + q) * 128 + df * 16 + lrow];
    }
    __syncthreads();

    if (wid == 0) {
        #pragma unroll
        for (int df = 0; df < 8; ++df) {
            #pragma unroll
            for (int q = 0; q < 4; ++q) {
                int rl = kgrp * 4 + q;
                int grow = row0 + rl;
                int d = df * 16 + lrow;
                float val = accpv[df][q] * invs2S[rl];
                if (!mskS[rl]) val = W[(size_t)winS[rl] * DD + d];
                out[EMB_OFF + (size_t)grow * DD + d] = val;
            }
        }
    }

    for (int rr = wid; rr < BR; rr += 4) {
        int grow = row0 + rr;
        int i1 = candS[rr * 2 + 0], i2 = candS[rr * 2 + 1];
        int mskr = mskS[rr];
        const float* hrow = hdn + (size_t)grow * HH;
        float4 h0 = *(const float4*)(hrow + lane * 8);
        float4 h1 = *(const float4*)(hrow + lane * 8 + 4);
        float v1, v2;
        {
            const float* wrow = W2Tf + (size_t)i1 * HH;
            float4 w0 = *(const float4*)(wrow + lane * 8);
            float4 w1 = *(const float4*)(wrow + lane * 8 + 4);
            float sdot = h0.x*w0.x + h0.y*w0.y + h0.z*w0.z + h0.w*w0.w
                       + h1.x*w1.x + h1.y*w1.y + h1.z*w1.z + h1.w*w1.w;
            #pragma unroll
            for (int mk = 1; mk < 64; mk <<= 1) sdot += __shfl_xor(sdot, mk);
            v1 = sdot + b2[i1] + gumbel[(size_t)grow * T_NT + i1];
        }
        {
            const float* wrow = W2Tf + (size_t)i2 * HH;
            float4 w0 = *(const float4*)(wrow + lane * 8);
            float4 w1 = *(const float4*)(wrow + lane * 8 + 4);
            float sdot = h0.x*w0.x + h0.y*w0.y + h0.z*w0.z + h0.w*w0.w
                       + h1.x*w1.x + h1.y*w1.y + h1.z*w1.z + h1.w*w1.w;
            #pragma unroll
            for (int mk = 1; mk < 64; mk <<= 1) sdot += __shfl_xor(sdot, mk);
            v2 = sdot + b2[i2] + gumbel[(size_t)grow * T_NT + i2];
        }
        int ibest = (v2 > v1 || (v2 == v1 && i2 < i1)) ? i2 : i1;
        int word = mskr ? tgt_ids[ibest] : winS[rr];
        if (lane == 0) out[WORD_OFF + grow] = (float)word;
        if (lane < MC_)
            out[CHAR_OFF + (size_t)grow * MC_ + lane] = (float)lut[(size_t)word * MC_ + lane];
    }

    if (t == 0) {
        float es = 0.f; int cs = 0;
        #pragma unroll
        for (int r = 0; r < BR; r++) { es += entS[r]; cs += mskS[r]; }
        entP[blockIdx.x] = es;
        cntP[blockIdx.x] = (float)cs;
    }
}

// ---------------- K4: final loss reduction ----------------
__global__ __launch_bounds__(256) void k4_loss(
    const float* __restrict__ entP, const float* __restrict__ cntP, float* __restrict__ out)
{
    __shared__ float sE[256], sC[256];
    int t = threadIdx.x;
    float e = 0.f, c = 0.f;
    for (int i = t; i < NBLK; i += 256) { e += entP[i]; c += cntP[i]; }
    sE[t] = e; sC[t] = c;
    __syncthreads();
    for (int s = 128; s > 0; s >>= 1) {
        if (t < s) { sE[t] += sE[t + s]; sC[t] += sC[t + s]; }
        __syncthreads();
    }
    if (t == 0) {
        float ns = fmaxf(sC[0], 1.0f);
        out[LOSS_OFF] = 0.03f * sE[0] / ns;
    }
}

// ---------------- launch ----------------
extern "C" void kernel_launch(void* const* d_in, const int* in_sizes, int n_in,
                              void* d_out, int out_size, void* d_ws, size_t ws_size,
                              hipStream_t stream) {
    const int* inp_word = (const int*)d_in[0];
    const int* keyword_table = (const int*)d_in[3];
    const int* tgt_ids = (const int*)d_in[4];
    const int* lut = (const int*)d_in[5];
    const float* gumbel = (const float*)d_in[6];
    const float* W = (const float*)d_in[7];
    const float* W1 = (const float*)d_in[8];
    const float* b1 = (const float*)d_in[9];
    const float* W2 = (const float*)d_in[10];
    const float* b2 = (const float*)d_in[11];
    float* out = (float*)d_out;

    float* wsf = (float*)d_ws;
    float* hdn = wsf + HDN_OFF;
    ushort_t* hdnB = (ushort_t*)(wsf + HDNB_OFF);
    float* W2Tf = wsf + W2T_OFF;
    ushort_t* W2q = (ushort_t*)(wsf + W2Q_OFF);
    ushort_t* wtgtT5 = (ushort_t*)(wsf + WTT5_OFF);
    float* wtgt = wsf + WT_OFF;
    float* invs2_g = wsf + WT_OFF;       // wtgt dead after k1b; reuse for invs2
    float* entP = wsf + ENT_OFF;
    float* cntP = wsf + CNT_OFF;
    ushort_t* S = (ushort_t*)(wsf + S_OFF);

    k1_gather<<<T_NT / 2, 256, 0, stream>>>(tgt_ids, W, wtgt);
    k1b_wtgtT5<<<64, 256, 0, stream>>>(wtgt, wtgtT5);
    k0_w2t<<<dim3(T_NT / 32, HH / 32), 256, 0, stream>>>(W2, W2Tf, W2q);
    k2_hdn<<<dim3(R_TOT / 64, HH / 64), 256, 0, stream>>>(inp_word, W, W1, b1, hdn, hdnB);

    if (ws_size >= (size_t)WS_NEED_FLOATS * sizeof(float)) {
        k3a_gemm<<<dim3(16, 128), 256, 0, stream>>>(hdnB, W2q, S);
        k3b_stream<<<NBLK, 256, 0, stream>>>(S, hdn, W2Tf, b2, gumbel,
                                             inp_word, keyword_table, tgt_ids, lut,
                                             invs2_g, out, entP, cntP);
        k3c_pv<<<512, 256, 0, stream>>>(S, wtgtT5, invs2_g, inp_word,
                                        keyword_table, W, out);
    } else {
        k3_fused_fb<<<NBLK, 256, 0, stream>>>(hdnB, hdn, W2q, W2Tf, b2, gumbel,
                                              inp_word, keyword_table, tgt_ids, lut,
                                              W, wtgtT5, out, entP, cntP);
    }
    k4_loss<<<1, 256, 0, stream>>>(entP, cntP, out);
}

// Round 20
// 196.134 us; speedup vs baseline: 1.4231x; 1.2741x over previous
//
#include <hip/hip_runtime.h>
#include <cstdint>

#define R_TOT 16384
#define T_NT  2048
#define DD    128
#define HH    512
#define MC_   20
#define BR    16
#define NBLK  1024
#define SPW   16

// Output layout (floats)
#define MASK_OFF 0
#define LOGP_OFF 16384
#define WORD_OFF 32768
#define CHAR_OFF 49152
#define EMB_OFF  376832
#define LOSS_OFF 2473984

// ws layout (float slots)
#define HDN_OFF   0
#define HDNB_OFF  8388608
#define W2T_OFF   12582912
#define W2Q_OFF   13631488
#define WTT5_OFF  14155776
#define WT_OFF    14286848
#define ENT_OFF   14548992
#define CNT_OFF   14550016
#define S_OFF     14551040
#define WS_NEED_FLOATS (S_OFF + 16777216)

typedef __attribute__((ext_vector_type(8))) short short8v;
typedef __attribute__((ext_vector_type(4))) float f32x4;
typedef unsigned short ushort_t;

__device__ __forceinline__ ushort_t f2bf(float f) {
    union { float f; unsigned int u; } v; v.f = f;
    unsigned int r = v.u + 0x7FFFu + ((v.u >> 16) & 1u);
    return (ushort_t)(r >> 16);
}
__device__ __forceinline__ float bf2f(ushort_t u) {
    union { unsigned int u; float f; } v; v.u = ((unsigned int)u) << 16;
    return v.f;
}
__device__ __forceinline__ void stage16(const ushort_t* gsrc, ushort_t* ldst) {
    __builtin_amdgcn_global_load_lds(
        (const __attribute__((address_space(1))) unsigned int*)gsrc,
        (__attribute__((address_space(3))) unsigned int*)ldst, 16, 0, 0);
}

// ---------------- K1: gather wtgt embeddings ----------------
__global__ __launch_bounds__(256) void k1_gather(
    const int* __restrict__ tgt_ids, const float* __restrict__ W, float* __restrict__ wtgt)
{
    int rr = blockIdx.x * 2 + (threadIdx.x >> 7);
    int d = threadIdx.x & 127;
    int wsrc = tgt_ids[rr];
    wtgt[(size_t)rr * DD + d] = W[(size_t)wsrc * DD + d];
}

// ---------------- K1b: wtgt -> wtgtT5 full-K PV B-fragment pack ----------------
__global__ __launch_bounds__(256) void k1b_wtgtT5(
    const float* __restrict__ wtgt, ushort_t* __restrict__ wtgtT5)
{
    const int sc = blockIdx.x, t = threadIdx.x;
    #pragma unroll
    for (int it = 0; it < 2; ++it) {
        int idx = it * 256 + t;
        int df = idx >> 6, lane = idx & 63;
        int lrow = lane & 15, kg = lane >> 4;
        ushort_t* dst = wtgtT5 + ((size_t)sc * 8 + df) * 512 + lane * 8;
        #pragma unroll
        for (int j = 0; j < 8; ++j) {
            int col = sc * 32 + (j < 4 ? kg * 4 + j : 16 + kg * 4 + (j - 4));
            dst[j] = f2bf(wtgt[(size_t)col * DD + df * 16 + lrow]);
        }
    }
}

// ---------------- K0: W2 -> W2Tf f32 + W2q lane-linear fragment pack ----------------
__global__ __launch_bounds__(256) void k0_w2t(
    const float* __restrict__ W2, float* __restrict__ W2Tf, ushort_t* __restrict__ W2q)
{
    __shared__ float tile[32][33];
    const int js = blockIdx.x, ks = blockIdx.y;
    const int cb = js * 32, kb = ks * 32;
    const int lx = threadIdx.x & 31, ly = threadIdx.x >> 5;
    #pragma unroll
    for (int i = 0; i < 32; i += 8)
        tile[ly + i][lx] = W2[(size_t)(kb + ly + i) * T_NT + cb + lx];
    __syncthreads();
    #pragma unroll
    for (int i = 0; i < 32; i += 8) {
        int c = cb + ly + i, k = kb + lx;
        W2Tf[(size_t)c * HH + k] = tile[lx][ly + i];
    }
    if (threadIdx.x < 128) {
        int c = threadIdx.x >> 2, kgrp = threadIdx.x & 3;
        int cs = c >> 4, lrow = c & 15;
        ushort_t* dst = W2q + (size_t)(((js * 2 + cs) * 16 + ks) * 512) + (kgrp * 16 + lrow) * 8;
        #pragma unroll
        for (int i = 0; i < 8; ++i)
            dst[i] = f2bf(tile[kgrp * 8 + i][c]);
    }
}

// ---------------- K2: hdn = relu(W[inp_word] @ W1 + b1), fp32 + bf16 ----------------
__global__ __launch_bounds__(256) void k2_hdn(
    const int* __restrict__ inp_word, const float* __restrict__ W,
    const float* __restrict__ W1, const float* __restrict__ b1,
    float* __restrict__ hdn, ushort_t* __restrict__ hdnB)
{
    __shared__ float As[16][64];
    __shared__ float Bs[16][64];
    const int t = threadIdx.x;
    const int bm = blockIdx.x * 64;
    const int bn = blockIdx.y * 64;
    const int tx = t & 15, ty = t >> 4;
    float acc[4][4] = {};
    for (int k0 = 0; k0 < DD; k0 += 16) {
        {
            int m = t >> 2, kq = t & 3;
            int wsrc = inp_word[bm + m];
            float4 v = *(const float4*)(W + (size_t)wsrc * DD + k0 + kq * 4);
            As[kq * 4 + 0][m] = v.x; As[kq * 4 + 1][m] = v.y;
            As[kq * 4 + 2][m] = v.z; As[kq * 4 + 3][m] = v.w;
        }
        {
            int k = t >> 4, nq = t & 15;
            *(float4*)(&Bs[k][nq * 4]) =
                *(const float4*)(W1 + (size_t)(k0 + k) * HH + bn + nq * 4);
        }
        __syncthreads();
        #pragma unroll
        for (int k = 0; k < 16; ++k) {
            float a[4], b[4];
            #pragma unroll
            for (int i = 0; i < 4; i++) a[i] = As[k][ty * 4 + i];
            #pragma unroll
            for (int j = 0; j < 4; j++) b[j] = Bs[k][tx * 4 + j];
            #pragma unroll
            for (int i = 0; i < 4; i++)
                #pragma unroll
                for (int j = 0; j < 4; j++)
                    acc[i][j] = fmaf(a[i], b[j], acc[i][j]);
        }
        __syncthreads();
    }
    #pragma unroll
    for (int i = 0; i < 4; i++) {
        int m = bm + ty * 4 + i;
        int n = bn + tx * 4;
        float4 v;
        v.x = fmaxf(acc[i][0] + b1[n + 0], 0.f);
        v.y = fmaxf(acc[i][1] + b1[n + 1], 0.f);
        v.z = fmaxf(acc[i][2] + b1[n + 2], 0.f);
        v.w = fmaxf(acc[i][3] + b1[n + 3], 0.f);
        *(float4*)(hdn + (size_t)m * HH + n) = v;
        ushort4 hb;
        hb.x = f2bf(v.x); hb.y = f2bf(v.y); hb.z = f2bf(v.z); hb.w = f2bf(v.w);
        *(ushort4*)(hdnB + (size_t)m * HH + n) = hb;
    }
}

// ---------------- K3a: staged GEMM S = hdn @ W2 (bf16 out) ----------------
__global__ __launch_bounds__(256) void k3a_gemm(
    const ushort_t* __restrict__ hdnB, const ushort_t* __restrict__ W2q,
    ushort_t* __restrict__ S)
{
    __shared__ ushort_t aT[2 * 4096];
    __shared__ ushort_t bT[2 * 4096];

    const int t = threadIdx.x;
    const int wid = t >> 6, lane = t & 63;
    const int lrow = lane & 15, kgrp = lane >> 4;
    const int nb = blockIdx.x, mb = blockIdx.y;
    const int wr = wid >> 1, wc = wid & 1;

    f32x4 acc[4][4];
    #pragma unroll
    for (int r = 0; r < 4; ++r)
        #pragma unroll
        for (int c = 0; c < 4; ++c) acc[r][c] = (f32x4){0.f, 0.f, 0.f, 0.f};

    #define K3A_STAGE(buf, ks)                                                          \
        {                                                                               \
            _Pragma("unroll")                                                           \
            for (int i = 0; i < 2; ++i) {                                               \
                int g = wid * 2 + i;                                                    \
                const ushort_t* asrc = hdnB + (size_t)(mb * 128 + g * 16 + lrow) * HH   \
                                       + (ks) * 32 + kgrp * 8;                          \
                stage16(asrc, &aT[(buf) * 4096 + g * 512 + lane * 8]);                  \
                const ushort_t* bsrc = W2q + (size_t)(((nb * 8 + g) * 16 + (ks)) * 512) \
                                       + lane * 8;                                      \
                stage16(bsrc, &bT[(buf) * 4096 + g * 512 + lane * 8]);                  \
            }                                                                           \
        }

    K3A_STAGE(0, 0);
    __syncthreads();

    for (int ks = 0; ks < 16; ++ks) {
        const int buf = ks & 1;
        if (ks + 1 < 16) K3A_STAGE(buf ^ 1, ks + 1);

        short8v af[4], bf[4];
        #pragma unroll
        for (int r = 0; r < 4; ++r)
            af[r] = *(const short8v*)&aT[buf * 4096 + (wr * 4 + r) * 512 + lane * 8];
        #pragma unroll
        for (int c = 0; c < 4; ++c)
            bf[c] = *(const short8v*)&bT[buf * 4096 + (wc * 4 + c) * 512 + lane * 8];

        #pragma unroll
        for (int r = 0; r < 4; ++r)
            #pragma unroll
            for (int c = 0; c < 4; ++c)
                acc[r][c] = __builtin_amdgcn_mfma_f32_16x16x32_bf16(bf[c], af[r], acc[r][c], 0, 0, 0);

        __syncthreads();
    }

    #pragma unroll
    for (int r = 0; r < 4; ++r) {
        #pragma unroll
        for (int c = 0; c < 4; ++c) {
            int row = mb * 128 + wr * 64 + r * 16 + lrow;
            int col = nb * 128 + wc * 64 + c * 16 + kgrp * 4;
            ushort4 o;
            o.x = f2bf(acc[r][c][0]); o.y = f2bf(acc[r][c][1]);
            o.z = f2bf(acc[r][c][2]); o.w = f2bf(acc[r][c][3]);
            *(ushort4*)(S + (size_t)row * T_NT + col) = o;
        }
    }
    #undef K3A_STAGE
}

// ---------------- K3bc: coalesced stats + LDS-P PV, fused ----------------
// 1024 blocks x 16 rows. Phase 1: wave wid -> rows wid*4..+4, lane-linear sweeps.
// Phase 2: wave wid -> d cols wid*32..+32, P from LDS, verified pav/wtgtT5 MFMA.
__global__ __launch_bounds__(256) void k3bc(
    const ushort_t* __restrict__ S, const float* __restrict__ hdn,
    const float* __restrict__ W2Tf, const float* __restrict__ b2,
    const float* __restrict__ gumbel, const int* __restrict__ inp_word,
    const int* __restrict__ keyword_table, const int* __restrict__ tgt_ids,
    const int* __restrict__ lut, const float* __restrict__ W,
    const ushort_t* __restrict__ wtgtT5,
    float* __restrict__ out, float* __restrict__ entP, float* __restrict__ cntP)
{
    __shared__ ushort_t PS[16 * 2056];     // P numerators, pad-8 rows (~66 KB)
    __shared__ float invs2S[16], entS[16];
    __shared__ int   mskS[16], winS[16], candS[32];

    const int t = threadIdx.x;
    const int wid = t >> 6, lane = t & 63;
    const int lrow = lane & 15, kgrp = lane >> 4;
    const int row0 = blockIdx.x * BR;

    // ---- phase 1: stats, coalesced ----
    for (int r = 0; r < 4; ++r) {
        const int rl = wid * 4 + r;
        const int grow = row0 + rl;
        const ushort_t* sR = S + (size_t)grow * T_NT;
        const float* gR = gumbel + (size_t)grow * T_NT;
        float m_ = -1e30f, sE_ = 0.f, sEl_ = 0.f, s2_ = 0.f;
        float a1_ = -1e30f, a2_ = -1e30f;
        int i1_ = 0, i2_ = 0;
        #pragma unroll
        for (int ch = 0; ch < 4; ++ch) {
            const int col = ch * 512 + lane * 8;
            ushort_t sv[8];
            *(uint4*)sv = *(const uint4*)(sR + col);
            float g[8];
            *(float4*)(g + 0) = *(const float4*)(gR + col);
            *(float4*)(g + 4) = *(const float4*)(gR + col + 4);
            float bb[8];
            *(float4*)(bb + 0) = *(const float4*)(b2 + col);
            *(float4*)(bb + 4) = *(const float4*)(b2 + col + 4);
            ushort_t pv[8];
            #pragma unroll
            for (int j = 0; j < 8; ++j) {
                float l = bf2f(sv[j]) + bb[j];
                m_ = fmaxf(m_, l);
                float e = __expf(l);
                sE_ += e; sEl_ = fmaf(e, l, sEl_);
                float a = l + g[j];
                float p = __expf(2.0f * a);
                s2_ += p;
                int ci = col + j;
                if (a > a1_) { a2_ = a1_; i2_ = i1_; a1_ = a; i1_ = ci; }
                else if (a > a2_) { a2_ = a; i2_ = ci; }
                pv[j] = f2bf(p);
            }
            *(uint4*)(&PS[rl * 2056 + col]) = *(uint4*)pv;
        }
        #pragma unroll
        for (int mk = 1; mk < 64; mk <<= 1) {
            m_ = fmaxf(m_, __shfl_xor(m_, mk));
            sE_ += __shfl_xor(sE_, mk);
            sEl_ += __shfl_xor(sEl_, mk);
            s2_ += __shfl_xor(s2_, mk);
            float ob1 = __shfl_xor(a1_, mk); int oj1 = __shfl_xor(i1_, mk);
            float ob2 = __shfl_xor(a2_, mk); int oj2 = __shfl_xor(i2_, mk);
            if (ob1 > a1_ || (ob1 == a1_ && oj1 < i1_)) {
                if (a1_ > ob2 || (a1_ == ob2 && i1_ < oj2)) { a2_ = a1_; i2_ = i1_; }
                else { a2_ = ob2; i2_ = oj2; }
                a1_ = ob1; i1_ = oj1;
            } else {
                if (ob1 > a2_) { a2_ = ob1; i2_ = oj1; }
            }
        }
        if (lane == 0) {
            int w_in = inp_word[grow];
            int msk = keyword_table[w_in] != 0;
            out[MASK_OFF + grow] = msk ? 1.0f : 0.0f;
            out[LOGP_OFF + grow] = msk ? m_ : 0.0f;
            invs2S[rl] = 1.0f / s2_;
            mskS[rl] = msk; winS[rl] = w_in;
            entS[rl] = msk ? (__logf(sE_) - sEl_ / sE_) : 0.0f;
            candS[rl * 2 + 0] = i1_;
            candS[rl * 2 + 1] = i2_;
        }
    }
    __syncthreads();

    // ---- phase 2: PV from LDS ----
    {
        const int df0 = wid * 2;
        f32x4 acc0 = (f32x4){0.f, 0.f, 0.f, 0.f}, acc1 = acc0;
        const ushort_t* pBase = &PS[lrow * 2056 + kgrp * 4];
        const ushort_t* vB = wtgtT5 + (size_t)df0 * 512 + lane * 8;
        for (int sc = 0; sc < 64; ++sc) {
            ushort4 pa = *(const ushort4*)(pBase + sc * 32);
            ushort4 pb = *(const ushort4*)(pBase + sc * 32 + 16);
            short8v pav;
            pav[0] = (short)pa.x; pav[1] = (short)pa.y; pav[2] = (short)pa.z; pav[3] = (short)pa.w;
            pav[4] = (short)pb.x; pav[5] = (short)pb.y; pav[6] = (short)pb.z; pav[7] = (short)pb.w;
            const ushort_t* vt = vB + (size_t)sc * 4096;
            short8v bv0 = *(const short8v*)vt;
            short8v bv1 = *(const short8v*)(vt + 512);
            acc0 = __builtin_amdgcn_mfma_f32_16x16x32_bf16(pav, bv0, acc0, 0, 0, 0);
            acc1 = __builtin_amdgcn_mfma_f32_16x16x32_bf16(pav, bv1, acc1, 0, 0, 0);
        }
        #pragma unroll
        for (int q = 0; q < 4; ++q) {
            int rl = kgrp * 4 + q;
            int grow = row0 + rl;
            float inv = invs2S[rl];
            int msk = mskS[rl], w_in = winS[rl];
            int d0 = df0 * 16 + lrow;
            float v0 = msk ? acc0[q] * inv : W[(size_t)w_in * DD + d0];
            out[EMB_OFF + (size_t)grow * DD + d0] = v0;
            int d1 = d0 + 16;
            float v1 = msk ? acc1[q] * inv : W[(size_t)w_in * DD + d1];
            out[EMB_OFF + (size_t)grow * DD + d1] = v1;
        }
    }

    // ---- repair + word/char ----
    for (int rr = wid; rr < BR; rr += 4) {
        int grow = row0 + rr;
        int i1 = candS[rr * 2 + 0], i2 = candS[rr * 2 + 1];
        int mskr = mskS[rr];
        const float* hrow = hdn + (size_t)grow * HH;
        float4 h0 = *(const float4*)(hrow + lane * 8);
        float4 h1 = *(const float4*)(hrow + lane * 8 + 4);
        float v1, v2;
        {
            const float* wrow = W2Tf + (size_t)i1 * HH;
            float4 w0 = *(const float4*)(wrow + lane * 8);
            float4 w1 = *(const float4*)(wrow + lane * 8 + 4);
            float sdot = h0.x*w0.x + h0.y*w0.y + h0.z*w0.z + h0.w*w0.w
                       + h1.x*w1.x + h1.y*w1.y + h1.z*w1.z + h1.w*w1.w;
            #pragma unroll
            for (int mk = 1; mk < 64; mk <<= 1) sdot += __shfl_xor(sdot, mk);
            v1 = sdot + b2[i1] + gumbel[(size_t)grow * T_NT + i1];
        }
        {
            const float* wrow = W2Tf + (size_t)i2 * HH;
            float4 w0 = *(const float4*)(wrow + lane * 8);
            float4 w1 = *(const float4*)(wrow + lane * 8 + 4);
            float sdot = h0.x*w0.x + h0.y*w0.y + h0.z*w0.z + h0.w*w0.w
                       + h1.x*w1.x + h1.y*w1.y + h1.z*w1.z + h1.w*w1.w;
            #pragma unroll
            for (int mk = 1; mk < 64; mk <<= 1) sdot += __shfl_xor(sdot, mk);
            v2 = sdot + b2[i2] + gumbel[(size_t)grow * T_NT + i2];
        }
        int ibest = (v2 > v1 || (v2 == v1 && i2 < i1)) ? i2 : i1;
        int word = mskr ? tgt_ids[ibest] : winS[rr];
        if (lane == 0) out[WORD_OFF + grow] = (float)word;
        if (lane < MC_)
            out[CHAR_OFF + (size_t)grow * MC_ + lane] = (float)lut[(size_t)word * MC_ + lane];
    }

    if (t == 0) {
        float es = 0.f; int cs = 0;
        #pragma unroll
        for (int r = 0; r < BR; r++) { es += entS[r]; cs += mskS[r]; }
        entP[blockIdx.x] = es;
        cntP[blockIdx.x] = (float)cs;
    }
}

// ---------------- K3 fallback (R14-best): fused S-MFMA + stats + PV ----------------
__global__ __launch_bounds__(256) void k3_fused_fb(
    const ushort_t* __restrict__ hdnB, const float* __restrict__ hdn,
    const ushort_t* __restrict__ W2q, const float* __restrict__ W2Tf,
    const float* __restrict__ b2, const float* __restrict__ gumbel,
    const int* __restrict__ inp_word, const int* __restrict__ keyword_table,
    const int* __restrict__ tgt_ids, const int* __restrict__ lut,
    const float* __restrict__ W, const ushort_t* __restrict__ wtgtT5,
    float* __restrict__ out, float* __restrict__ entP, float* __restrict__ cntP)
{
    __shared__ float bigS[6144];
    __shared__ float statP[4][16][8];
    __shared__ int   candS[BR * 2];
    __shared__ float invs2S[BR], entS[BR];
    __shared__ int   mskS[BR], winS[BR];

    const int t = threadIdx.x;
    const int wid = t >> 6, lane = t & 63;
    const int lrow = lane & 15, kgrp = lane >> 4;
    const int row0 = blockIdx.x * BR;

    ushort_t* aP = (ushort_t*)bigS;
    #pragma unroll
    for (int it = 0; it < 4; ++it) {
        int gid = it * 256 + t;
        int ks = gid >> 6, l2 = gid & 63;
        int lr = l2 & 15, kg = l2 >> 4;
        uint4 v = *(const uint4*)(hdnB + (size_t)(row0 + lr) * HH + ks * 32 + kg * 8);
        *(uint4*)(aP + gid * 8) = v;
    }
    __syncthreads();

    const int scq = (int)((blockIdx.x + wid) & 3);
    const ushort_t* aRd = aP + lane * 8;
    const float* gRow = gumbel + (size_t)(row0 + lrow) * T_NT + kgrp * 4;

    float m_ = -1e30f, sE_ = 0.f, sEl_ = 0.f, s2_ = 0.f;
    float a1_ = -1e30f, a2_ = -1e30f;
    int i1_ = 0, i2_ = 0;
    f32x4 accpv[8];
    #pragma unroll
    for (int df = 0; df < 8; ++df) accpv[df] = (f32x4){0.f, 0.f, 0.f, 0.f};

    f32x4 ga = *(const f32x4*)(gRow + scq * 32);
    f32x4 gb = *(const f32x4*)(gRow + scq * 32 + 16);

    for (int s = 0; s < SPW; ++s) {
        const int sc = scq + 4 * s;
        const int scn = scq + 4 * ((s + 1) & 15);
        f32x4 gna = *(const f32x4*)(gRow + scn * 32);
        f32x4 gnb = *(const f32x4*)(gRow + scn * 32 + 16);
        f32x4 b2a = *(const f32x4*)(b2 + sc * 32 + kgrp * 4);
        f32x4 b2b = *(const f32x4*)(b2 + sc * 32 + kgrp * 4 + 16);

        const ushort_t* w2a = W2q + (size_t)sc * 16384 + lane * 8;
        f32x4 c0a = (f32x4){0.f,0.f,0.f,0.f}, c0b = c0a, c1a = c0a, c1b = c0a;
        #pragma unroll
        for (int ks = 0; ks < 16; ks += 2) {
            short8v avk0 = *(const short8v*)(aRd + (ks + 0) * 512);
            short8v avk1 = *(const short8v*)(aRd + (ks + 1) * 512);
            c0a = __builtin_amdgcn_mfma_f32_16x16x32_bf16(*(const short8v*)(w2a + (ks+0)*512), avk0, c0a, 0, 0, 0);
            c1a = __builtin_amdgcn_mfma_f32_16x16x32_bf16(*(const short8v*)(w2a + 8192 + (ks+0)*512), avk0, c1a, 0, 0, 0);
            c0b = __builtin_amdgcn_mfma_f32_16x16x32_bf16(*(const short8v*)(w2a + (ks+1)*512), avk1, c0b, 0, 0, 0);
            c1b = __builtin_amdgcn_mfma_f32_16x16x32_bf16(*(const short8v*)(w2a + 8192 + (ks+1)*512), avk1, c1b, 0, 0, 0);
        }
        f32x4 acc0 = c0a + c0b;
        f32x4 acc1 = c1a + c1b;

        const ushort_t* vt = wtgtT5 + (size_t)sc * 4096 + lane * 8;
        short8v bvf[8];
        #pragma unroll
        for (int df = 0; df < 8; ++df) bvf[df] = *(const short8v*)(vt + df * 512);

        short8v pav;
        const int colb = sc * 32 + kgrp * 4;
        #pragma unroll
        for (int q = 0; q < 4; ++q) {
            float l0 = acc0[q] + b2a[q];
            m_ = fmaxf(m_, l0);
            float e0 = __expf(l0);
            sE_ += e0; sEl_ = fmaf(e0, l0, sEl_);
            float aa0 = l0 + ga[q];
            float p0 = __expf(2.0f * aa0);
            s2_ += p0;
            if (aa0 > a1_) { a2_ = a1_; i2_ = i1_; a1_ = aa0; i1_ = colb + q; }
            else if (aa0 > a2_) { a2_ = aa0; i2_ = colb + q; }
            pav[q] = (short)f2bf(p0);
            float l1 = acc1[q] + b2b[q];
            m_ = fmaxf(m_, l1);
            float e1 = __expf(l1);
            sE_ += e1; sEl_ = fmaf(e1, l1, sEl_);
            float aa1 = l1 + gb[q];
            float p1 = __expf(2.0f * aa1);
            s2_ += p1;
            if (aa1 > a1_) { a2_ = a1_; i2_ = i1_; a1_ = aa1; i1_ = colb + 16 + q; }
            else if (aa1 > a2_) { a2_ = aa1; i2_ = colb + 16 + q; }
            pav[4 + q] = (short)f2bf(p1);
        }

        #pragma unroll
        for (int df = 0; df < 8; ++df)
            accpv[df] = __builtin_amdgcn_mfma_f32_16x16x32_bf16(pav, bvf[df], accpv[df], 0, 0, 0);

        ga = gna; gb = gnb;
    }

    #pragma unroll
    for (int mk = 16; mk < 64; mk <<= 1) {
        m_ = fmaxf(m_, __shfl_xor(m_, mk));
        sE_ += __shfl_xor(sE_, mk);
        sEl_ += __shfl_xor(sEl_, mk);
        s2_ += __shfl_xor(s2_, mk);
        float ob1 = __shfl_xor(a1_, mk); int oj1 = __shfl_xor(i1_, mk);
        float ob2 = __shfl_xor(a2_, mk); int oj2 = __shfl_xor(i2_, mk);
        if (ob1 > a1_ || (ob1 == a1_ && oj1 < i1_)) {
            if (a1_ > ob2 || (a1_ == ob2 && i1_ < oj2)) { a2_ = a1_; i2_ = i1_; }
            else { a2_ = ob2; i2_ = oj2; }
            a1_ = ob1; i1_ = oj1;
        } else {
            if (ob1 > a2_) { a2_ = ob1; i2_ = oj1; }
        }
    }

    __syncthreads();
    if (lane < 16) {
        float* st = &statP[wid][lane][0];
        st[0] = m_; st[1] = sE_; st[2] = sEl_; st[3] = s2_;
        st[4] = a1_; st[5] = __int_as_float(i1_);
        st[6] = a2_; st[7] = __int_as_float(i2_);
    }
    if (wid >= 1) {
        float* scr = bigS + (wid - 1) * 2048;
        #pragma unroll
        for (int df = 0; df < 8; ++df)
            #pragma unroll
            for (int q = 0; q < 4; ++q)
                scr[(kgrp * 4 + q) * 128 + df * 16 + lrow] = accpv[df][q];
    }
    __syncthreads();

    if (wid == 0) {
        if (lane < 16) {
            float M = -1e30f, SE = 0.f, SEL = 0.f, S2 = 0.f;
            float A1 = -1e30f, A2 = -1e30f; int I1 = 0, I2 = 0;
            #pragma unroll
            for (int w = 0; w < 4; ++w) {
                const float* st = &statP[w][lane][0];
                float ob1 = st[4]; int oj1 = __float_as_int(st[5]);
                float ob2 = st[6]; int oj2 = __float_as_int(st[7]);
                M = fmaxf(M, st[0]); SE += st[1]; SEL += st[2]; S2 += st[3];
                if (ob1 > A1 || (ob1 == A1 && oj1 < I1)) {
                    if (A1 > ob2 || (A1 == ob2 && I1 < oj2)) { A2 = A1; I2 = I1; }
                    else { A2 = ob2; I2 = oj2; }
                    A1 = ob1; I1 = oj1;
                } else {
                    if (ob1 > A2) { A2 = ob1; I2 = oj1; }
                }
            }
            int grow = row0 + lane;
            int w_in = inp_word[grow];
            int msk = keyword_table[w_in] != 0;
            out[MASK_OFF + grow] = msk ? 1.0f : 0.0f;
            out[LOGP_OFF + grow] = msk ? M : 0.0f;
            invs2S[lane] = 1.0f / S2;
            mskS[lane] = msk;
            winS[lane] = w_in;
            entS[lane] = msk ? (__logf(SE) - SEL / SE) : 0.0f;
            candS[lane * 2 + 0] = I1;
            candS[lane * 2 + 1] = I2;
        }
        #pragma unroll
        for (int df = 0; df < 8; ++df)
            #pragma unroll
            for (int q = 0; q < 4; ++q)
                accpv[df][q] += bigS[0 * 2048 + (kgrp * 4 + q) * 128 + df * 16 + lrow]
                              + bigS[1 * 2048 + (kgrp * 4 + q) * 128 + df * 16 + lrow]
                              + bigS[2 * 2048 + (kgrp * 4 + q) * 128 + df * 16 + lrow];
    }
    __syncthreads();

    if (wid == 0) {
        #pragma unroll
        for (int df = 0; df < 8; ++df) {
            #pragma unroll
            for (int q = 0; q < 4; ++q) {
                int rl = kgrp * 4 + q;
                int grow = row0 + rl;
                int d = df * 16 + lrow;
                float val = accpv[df][q] * invs2S[rl];
                if (!mskS[rl]) val = W[(size_t)winS[rl] * DD + d];
                out[EMB_OFF + (size_t)grow * DD + d] = val;
            }
        }
    }

    for (int rr = wid; rr < BR; rr += 4) {
        int grow = row0 + rr;
        int i1 = candS[rr * 2 + 0], i2 = candS[rr * 2 + 1];
        int mskr = mskS[rr];
        const float* hrow = hdn + (size_t)grow * HH;
        float4 h0 = *(const float4*)(hrow + lane * 8);
        float4 h1 = *(const float4*)(hrow + lane * 8 + 4);
        float v1, v2;
        {
            const float* wrow = W2Tf + (size_t)i1 * HH;
            float4 w0 = *(const float4*)(wrow + lane * 8);
            float4 w1 = *(const float4*)(wrow + lane * 8 + 4);
            float sdot = h0.x*w0.x + h0.y*w0.y + h0.z*w0.z + h0.w*w0.w
                       + h1.x*w1.x + h1.y*w1.y + h1.z*w1.z + h1.w*w1.w;
            #pragma unroll
            for (int mk = 1; mk < 64; mk <<= 1) sdot += __shfl_xor(sdot, mk);
            v1 = sdot + b2[i1] + gumbel[(size_t)grow * T_NT + i1];
        }
        {
            const float* wrow = W2Tf + (size_t)i2 * HH;
            float4 w0 = *(const float4*)(wrow + lane * 8);
            float4 w1 = *(const float4*)(wrow + lane * 8 + 4);
            float sdot = h0.x*w0.x + h0.y*w0.y + h0.z*w0.z + h0.w*w0.w
                       + h1.x*w1.x + h1.y*w1.y + h1.z*w1.z + h1.w*w1.w;
            #pragma unroll
            for (int mk = 1; mk < 64; mk <<= 1) sdot += __shfl_xor(sdot, mk);
            v2 = sdot + b2[i2] + gumbel[(size_t)grow * T_NT + i2];
        }
        int ibest = (v2 > v1 || (v2 == v1 && i2 < i1)) ? i2 : i1;
        int word = mskr ? tgt_ids[ibest] : winS[rr];
        if (lane == 0) out[WORD_OFF + grow] = (float)word;
        if (lane < MC_)
            out[CHAR_OFF + (size_t)grow * MC_ + lane] = (float)lut[(size_t)word * MC_ + lane];
    }

    if (t == 0) {
        float es = 0.f; int cs = 0;
        #pragma unroll
        for (int r = 0; r < BR; r++) { es += entS[r]; cs += mskS[r]; }
        entP[blockIdx.x] = es;
        cntP[blockIdx.x] = (float)cs;
    }
}

// ---------------- K4: final loss reduction ----------------
__global__ __launch_bounds__(256) void k4_loss(
    const float* __restrict__ entP, const float* __restrict__ cntP, float* __restrict__ out)
{
    __shared__ float sE[256], sC[256];
    int t = threadIdx.x;
    float e = 0.f, c = 0.f;
    for (int i = t; i < NBLK; i += 256) { e += entP[i]; c += cntP[i]; }
    sE[t] = e; sC[t] = c;
    __syncthreads();
    for (int s = 128; s > 0; s >>= 1) {
        if (t < s) { sE[t] += sE[t + s]; sC[t] += sC[t + s]; }
        __syncthreads();
    }
    if (t == 0) {
        float ns = fmaxf(sC[0], 1.0f);
        out[LOSS_OFF] = 0.03f * sE[0] / ns;
    }
}

// ---------------- launch ----------------
extern "C" void kernel_launch(void* const* d_in, const int* in_sizes, int n_in,
                              void* d_out, int out_size, void* d_ws, size_t ws_size,
                              hipStream_t stream) {
    const int* inp_word = (const int*)d_in[0];
    const int* keyword_table = (const int*)d_in[3];
    const int* tgt_ids = (const int*)d_in[4];
    const int* lut = (const int*)d_in[5];
    const float* gumbel = (const float*)d_in[6];
    const float* W = (const float*)d_in[7];
    const float* W1 = (const float*)d_in[8];
    const float* b1 = (const float*)d_in[9];
    const float* W2 = (const float*)d_in[10];
    const float* b2 = (const float*)d_in[11];
    float* out = (float*)d_out;

    float* wsf = (float*)d_ws;
    float* hdn = wsf + HDN_OFF;
    ushort_t* hdnB = (ushort_t*)(wsf + HDNB_OFF);
    float* W2Tf = wsf + W2T_OFF;
    ushort_t* W2q = (ushort_t*)(wsf + W2Q_OFF);
    ushort_t* wtgtT5 = (ushort_t*)(wsf + WTT5_OFF);
    float* wtgt = wsf + WT_OFF;
    float* entP = wsf + ENT_OFF;
    float* cntP = wsf + CNT_OFF;
    ushort_t* S = (ushort_t*)(wsf + S_OFF);

    k1_gather<<<T_NT / 2, 256, 0, stream>>>(tgt_ids, W, wtgt);
    k1b_wtgtT5<<<64, 256, 0, stream>>>(wtgt, wtgtT5);
    k0_w2t<<<dim3(T_NT / 32, HH / 32), 256, 0, stream>>>(W2, W2Tf, W2q);
    k2_hdn<<<dim3(R_TOT / 64, HH / 64), 256, 0, stream>>>(inp_word, W, W1, b1, hdn, hdnB);

    if (ws_size >= (size_t)WS_NEED_FLOATS * sizeof(float)) {
        k3a_gemm<<<dim3(16, 128), 256, 0, stream>>>(hdnB, W2q, S);
        k3bc<<<NBLK, 256, 0, stream>>>(S, hdn, W2Tf, b2, gumbel,
                                       inp_word, keyword_table, tgt_ids, lut,
                                       W, wtgtT5, out, entP, cntP);
    } else {
        k3_fused_fb<<<NBLK, 256, 0, stream>>>(hdnB, hdn, W2q, W2Tf, b2, gumbel,
                                              inp_word, keyword_table, tgt_ids, lut,
                                              W, wtgtT5, out, entP, cntP);
    }
    k4_loss<<<1, 256, 0, stream>>>(entP, cntP, out);
}